// Round 12
// baseline (15737.752 us; speedup 1.0000x reference)
//
#include <hip/hip_runtime.h>
#include <cstdint>

#define BB 8
#define NN 16384
#define DD 128
#define KK 10
#define N_ITERS 7
#define LN_EPS 1e-5f
#define ATT_EPS 1e-8f
#define SCALE 0.08838834764831845f   // D^-0.5

#define LNR 64                 // rows per ln block
#define LNCH (NN / LNR)        // 256 chunks per batch
#define NB 128                 // n per attn block
#define NCH (NN / NB)          // 128 chunks per batch
#define NBLK (BB * NCH)        // 1024 fused-grid blocks (= 4/CU exactly)
#define NGRP 64                // barrier groups
#define SLOTBLK (BB * KK)      // 80 blocks do slot phase

typedef __attribute__((ext_vector_type(8))) short bf16x8;
typedef __attribute__((ext_vector_type(4))) float f32x4;

__device__ inline ushort f2bf(float f) {
    uint u = __builtin_bit_cast(uint, f);
    u += 0x7FFFu + ((u >> 16) & 1u);
    return (ushort)(u >> 16);
}
__device__ inline float bf2f(ushort u) {
    return __builtin_bit_cast(float, ((uint)u) << 16);
}

// ---- workspace layout (float units) ----
#define OFF_XN    ((size_t)0)
#define OFF_Q     (OFF_XN + (size_t)BB * NN * DD / 2)
#define OFF_QC0   (OFF_Q + (size_t)BB * KK * DD)
#define OFF_SLOTS (OFF_QC0 + 128)
#define OFF_UPART (OFF_SLOTS + (size_t)BB * KK * DD)
#define OFF_DPART (OFF_UPART + (size_t)BB * NCH * KK * DD)
#define OFF_SXP   (OFF_DPART + (size_t)BB * NCH * KK)
#define OFF_SUMX  (OFF_SXP + (size_t)BB * LNCH * DD)
#define OFF_WIHT  (OFF_SUMX + (size_t)BB * DD)
#define OFF_WHHT  (OFF_WIHT + (size_t)3 * DD * DD)
#define OFF_WVIH  (OFF_WHHT + (size_t)3 * DD * DD)
#define OFF_BVIH  (OFF_WVIH + (size_t)DD * 3 * DD)
#define OFF_M     (OFF_BVIH + (size_t)3 * DD)
#define OFF_V0    (OFF_M + (size_t)DD * DD)
#define OFF_WQBK  (OFF_V0 + (size_t)DD)
#define OFF_C1    (OFF_WQBK + (size_t)DD)
#define OFF_BAR   (OFF_C1 + 8)
#define BAR_INTS  (NGRP * 32 + 2)

// ------------------------------------------------------------------
__global__ void k_zero(int* __restrict__ bar) {
    int t = blockIdx.x * 256 + threadIdx.x;
    for (int i = t; i < BAR_INTS; i += 256) bar[i] = 0;
}

// ------------------------------------------------------------------
// Prep: transposes + folded weight products (one-time, fp32 exact).
__global__ void k_prep(const float* __restrict__ Wih, const float* __restrict__ Whh,
                       const float* __restrict__ Wq, const float* __restrict__ Wk,
                       const float* __restrict__ Wv,
                       const float* __restrict__ bih, const float* __restrict__ bv,
                       const float* __restrict__ bq, const float* __restrict__ bk,
                       float* __restrict__ WihT, float* __restrict__ WhhT,
                       float* __restrict__ Wvih, float* __restrict__ bvih,
                       float* __restrict__ M, float* __restrict__ v0,
                       float* __restrict__ wqbk, float* __restrict__ c1) {
    int idx = blockIdx.x * 256 + threadIdx.x;
    if (idx < 3 * DD * DD) {
        int d = idx / (3 * DD);
        int j = idx % (3 * DD);
        WihT[idx] = Wih[j * DD + d];
        WhhT[idx] = Whh[j * DD + d];
    } else if (idx < 2 * 3 * DD * DD) {
        int i = idx - 3 * DD * DD;
        int d = i / (3 * DD), t = i % (3 * DD);
        float s = 0.f;
        for (int e = 0; e < DD; e++) s += Wv[d * DD + e] * Wih[t * DD + e];
        Wvih[i] = s;
    } else if (idx < 2 * 3 * DD * DD + 3 * DD) {
        int t = idx - 2 * 3 * DD * DD;
        float s = bih[t];
        for (int e = 0; e < DD; e++) s += bv[e] * Wih[t * DD + e];
        bvih[t] = s;
    } else if (idx < 2 * 3 * DD * DD + 3 * DD + DD * DD) {
        int i = idx - (2 * 3 * DD * DD + 3 * DD);
        int d = i / DD, e = i % DD;
        float s = 0.f;
        for (int j = 0; j < DD; j++) s += Wq[d * DD + j] * Wk[e * DD + j];
        M[i] = s;
    } else if (idx < 2 * 3 * DD * DD + 3 * DD + DD * DD + DD) {
        int e = idx - (2 * 3 * DD * DD + 3 * DD + DD * DD);
        float s = 0.f;
        for (int j = 0; j < DD; j++) s += bq[j] * Wk[e * DD + j];
        v0[e] = s;
    } else if (idx < 2 * 3 * DD * DD + 3 * DD + DD * DD + 2 * DD) {
        int d = idx - (2 * 3 * DD * DD + 3 * DD + DD * DD + DD);
        float s = 0.f;
        for (int j = 0; j < DD; j++) s += Wq[d * DD + j] * bk[j];
        wqbk[d] = s;
    } else if (idx == 2 * 3 * DD * DD + 3 * DD + DD * DD + 2 * DD) {
        float s = 0.f;
        for (int j = 0; j < DD; j++) s += bq[j] * bk[j];
        c1[0] = s;
    }
}
#define PREP_TOTAL (2 * 3 * DD * DD + 3 * DD + DD * DD + 2 * DD + 1)

// ------------------------------------------------------------------
// Pure LayerNorm: x -> xn (row-major bf16) + sxp (partial column sums).
__global__ __launch_bounds__(256) void k_ln(
        const float* __restrict__ x,
        const float* __restrict__ g_in, const float* __restrict__ b_in,
        ushort* __restrict__ xn, float* __restrict__ sxp) {
    __shared__ ushort xt[LNR][136];

    int t = threadIdx.x, blk = blockIdx.x;
    int b = blk >> 8, ch = blk & (LNCH - 1);
    int n0 = ch * LNR;

    {
        int r = t >> 2, p = t & 3;
        const float4* xr = (const float4*)(x + ((size_t)(b * NN + n0 + r)) * DD + p * 32);
        float4 xv[8];
        float s = 0.f, sq = 0.f;
        #pragma unroll
        for (int i = 0; i < 8; i++) {
            xv[i] = xr[i];
            s  += xv[i].x + xv[i].y + xv[i].z + xv[i].w;
            sq += xv[i].x * xv[i].x + xv[i].y * xv[i].y +
                  xv[i].z * xv[i].z + xv[i].w * xv[i].w;
        }
        s += __shfl_xor(s, 1);  sq += __shfl_xor(sq, 1);
        s += __shfl_xor(s, 2);  sq += __shfl_xor(sq, 2);
        float mean = s * (1.0f / DD);
        float var  = sq * (1.0f / DD) - mean * mean;
        float rstd = rsqrtf(var + LN_EPS);
        ushort* xno = xn + ((size_t)(b * NN + n0 + r)) * DD + p * 32;
        #pragma unroll
        for (int i = 0; i < 8; i++) {
            int c0 = p * 32 + i * 4;
            ushort4 uv;
            uv.x = f2bf((xv[i].x - mean) * rstd * g_in[c0 + 0] + b_in[c0 + 0]);
            uv.y = f2bf((xv[i].y - mean) * rstd * g_in[c0 + 1] + b_in[c0 + 1]);
            uv.z = f2bf((xv[i].z - mean) * rstd * g_in[c0 + 2] + b_in[c0 + 2]);
            uv.w = f2bf((xv[i].w - mean) * rstd * g_in[c0 + 3] + b_in[c0 + 3]);
            *(ushort4*)&xt[r][c0] = uv;
            *(ushort4*)(xno + i * 4) = uv;
        }
    }
    __syncthreads();

    {
        int c = t >> 1, h = t & 1;
        float sx = 0.f;
        #pragma unroll
        for (int rr = 0; rr < 32; rr++) sx += bf2f(xt[h * 32 + rr][c]);
        sx += __shfl_xor(sx, 1);
        if (h == 0) sxp[((size_t)(b * LNCH + ch)) * DD + c] = sx;
    }
}

// ------------------------------------------------------------------
__global__ __launch_bounds__(512) void k_sumx(const float* __restrict__ sxp,
                                              float* __restrict__ sumx) {
    int b = blockIdx.x, t = threadIdx.x;
    int c = t & 127, g = t >> 7;
    __shared__ float part[4][DD];
    float s = 0.f;
    for (int cb = g * 64; cb < (g + 1) * 64; cb++)
        s += sxp[((size_t)(b * LNCH + cb)) * DD + c];
    part[g][c] = s;
    __syncthreads();
    if (t < DD) sumx[b * DD + t] = part[0][t] + part[1][t] + part[2][t] + part[3][t];
}

// ------------------------------------------------------------------
// Fused persistent kernel: k_init + 7 x (attn ; slot) with grid barriers.
// 1024 blocks x 256 threads = exactly 4 blocks/CU (LDS 38.8 KB).
__global__ __launch_bounds__(256, 4) void k_fused(
        const ushort* __restrict__ xn,
        const float* __restrict__ noise, const float* __restrict__ mu,
        const float* __restrict__ logsigma,
        const float* __restrict__ sumx,
        const float* __restrict__ Wvih, const float* __restrict__ bvih,
        const float* __restrict__ WhhT, const float* __restrict__ bhh,
        const float* __restrict__ W1, const float* __restrict__ b1,
        const float* __restrict__ W2, const float* __restrict__ b2,
        const float* __restrict__ M, const float* __restrict__ v0,
        const float* __restrict__ wqbk, const float* __restrict__ c1,
        const float* __restrict__ g_ff, const float* __restrict__ b_ff,
        const float* __restrict__ g_sl, const float* __restrict__ b_sl,
        float* __restrict__ slots, float* __restrict__ qp,
        float* __restrict__ qc0,
        float* __restrict__ upart, float* __restrict__ dpart,
        int* __restrict__ bar,
        float* __restrict__ out_nf, float* __restrict__ out_adj,
        float* __restrict__ out_s) {
    __shared__ char xnlds[32768];       // persistent [n(128)][d(128)] bf16, swizzled
    __shared__ char ubuf[5696];         // phase A: qpbuf[2176]u16 | phase B: floats
    __shared__ float red2[4][16];
    __shared__ float c0s[16];
#define QLDS(r, c) ((ushort*)ubuf)[(r) * 136 + (c)]
#define PLDS(n, k) ((ushort*)ubuf)[(n) * 17 + (k)]
#define FB ((float*)ubuf)
#define p_lds (FB)            /* [128] */
#define tmpb  (FB + 128)      /* [128] */
#define y_lds (FB + 256)      /* [128] */
#define gi_l  (FB + 384)      /* [384] */
#define gh_l  (FB + 768)      /* [384] */
#define upr_l (FB + 1152)     /* [2][128]; pp aliases this */
#define red_l (FB + 1408)     /* [8] */

    int t = threadIdx.x;
    int bid = blockIdx.x;
    int b  = bid >> 7;
    int ch = bid & (NCH - 1);
    int n0 = ch * NB;
    int w = t >> 6, l = t & 63;
    int lc = l & 15, lg = l >> 4;
    int* gcnt = bar;                 // [NGRP*32], padded
    int* tcnt = bar + NGRP * 32;
    int* rel  = bar + NGRP * 32 + 1;

    // ---- stage persistent xn tile (2048 x 16B chunks, swizzled) ----
    {
        const uint4* src = (const uint4*)(xn + ((size_t)(b * NN + n0)) * DD);
        #pragma unroll
        for (int i = 0; i < 8; i++) {
            int c = t + i * 256;
            uint4 v = src[c];
            int n = c >> 4;
            uint bo = ((uint)c * 16) ^ (((uint)n & 7) << 4);
            *(uint4*)(xnlds + bo) = v;
        }
    }

    // ---- init phase (bid < 80): slots, qp, qc0 ----
    if (bid < SLOTBLK) {
        int bk_ = bid;
        float sv = 0.f, sq = 0.f, s0 = 0.f;
        if (t < DD) {
            s0 = mu[t] + __expf(logsigma[t]) * noise[bk_ * DD + t];
            slots[bk_ * DD + t] = s0;
            sv = s0; sq = s0 * s0;
        }
        #pragma unroll
        for (int o = 32; o > 0; o >>= 1) { sv += __shfl_xor(sv, o); sq += __shfl_xor(sq, o); }
        if ((t & 63) == 0) { red_l[w * 2] = sv; red_l[w * 2 + 1] = sq; }
        __syncthreads();
        float mean = (red_l[0] + red_l[2]) * (1.0f / DD);
        float var  = (red_l[1] + red_l[3]) * (1.0f / DD) - mean * mean;
        float rstd = rsqrtf(var + LN_EPS);
        if (t < DD) tmpb[t] = (s0 - mean) * rstd * g_sl[t] + b_sl[t];
        __syncthreads();
        if (t < DD) {
            float qq = v0[t];
            for (int d = 0; d < DD; d++) qq += tmpb[d] * M[d * DD + t];
            qp[bk_ * DD + t] = SCALE * qq;
        }
        {
            float cp = (t < DD) ? tmpb[t] * wqbk[t] : 0.f;
            #pragma unroll
            for (int o = 32; o > 0; o >>= 1) cp += __shfl_xor(cp, o);
            if (t < 128 && (t & 63) == 0) red_l[4 + w] = cp;
        }
        __syncthreads();
        if (t == 0) qc0[bk_] = SCALE * (red_l[4] + red_l[5] + c1[0]);
    }

    // ---- grid barrier helper (monotonic, hierarchical) ----
    auto gridbar = [&](int s) {
        __syncthreads();
        if (t == 0) {
            __threadfence();
            int g = bid & (NGRP - 1);
            if (atomicAdd(&gcnt[g * 32], 1) == (s + 1) * (NBLK / NGRP) - 1) {
                if (atomicAdd(tcnt, 1) == (s + 1) * NGRP - 1) {
                    __hip_atomic_store(rel, s + 1, __ATOMIC_RELEASE,
                                       __HIP_MEMORY_SCOPE_AGENT);
                }
            }
            while (__hip_atomic_load(rel, __ATOMIC_ACQUIRE,
                                     __HIP_MEMORY_SCOPE_AGENT) < s + 1)
                __builtin_amdgcn_s_sleep(2);
        }
        __syncthreads();
        __threadfence();
    };

    gridbar(0);

    for (int it = 0; it < N_ITERS; it++) {
        int last = (it == N_ITERS - 1);
        // ================= phase A: attention =================
        for (int j = t; j < 16 * DD; j += 256) {
            int row = j >> 7, col = j & 127;
            float v = (row < KK) ? qp[((size_t)b * KK + row) * DD + col] : 0.f;
            QLDS(row, col) = f2bf(v);
        }
        if (t < 16) c0s[t] = (t < KK) ? qc0[b * KK + t] : 0.f;
        __syncthreads();

        bf16x8 qb[4];
        #pragma unroll
        for (int ks = 0; ks < 4; ks++)
            qb[ks] = *(const bf16x8*)&QLDS(lc, ks * 32 + lg * 8);
        float c0v = c0s[lc];
        __syncthreads();   // ubuf now reusable as plds

        float dsum = 0.f;
        bool valid = lc < KK;
        #pragma unroll
        for (int tt = 0; tt < 2; tt++) {
            int nt = w * 2 + tt;
            int nrow = nt * 16 + lc;
            f32x4 acc = (f32x4){0.f, 0.f, 0.f, 0.f};
            #pragma unroll
            for (int ks = 0; ks < 4; ks++) {
                uint bo = ((uint)nrow * 256 + (uint)(ks * 32 + lg * 8) * 2)
                          ^ (((uint)nrow & 7) << 4);
                bf16x8 a = *(const bf16x8*)(xnlds + bo);
                acc = __builtin_amdgcn_mfma_f32_16x16x32_bf16(a, qb[ks], acc, 0, 0, 0);
            }
            #pragma unroll
            for (int r = 0; r < 4; r++) {
                float v = acc[r] + c0v;
                float m = valid ? v : -3.0e38f;
                m = fmaxf(m, __shfl_xor(m, 1));
                m = fmaxf(m, __shfl_xor(m, 2));
                m = fmaxf(m, __shfl_xor(m, 4));
                m = fmaxf(m, __shfl_xor(m, 8));
                float e = valid ? __expf(v - m) : 0.f;
                float s = e;
                s += __shfl_xor(s, 1);
                s += __shfl_xor(s, 2);
                s += __shfl_xor(s, 4);
                s += __shfl_xor(s, 8);
                float p = e / s;
                dsum += p;
                PLDS(nt * 16 + lg * 4 + r, lc) = f2bf(p);
            }
        }
        dsum += __shfl_xor(dsum, 16);
        dsum += __shfl_xor(dsum, 32);
        if (l < 16) red2[w][l] = dsum;
        __syncthreads();
        if (t < KK)
            dpart[((size_t)b * NCH + ch) * KK + t] =
                red2[0][t] + red2[1][t] + red2[2][t] + red2[3][t];

        bf16x8 pa[4];
        #pragma unroll
        for (int ks = 0; ks < 4; ks++) {
            #pragma unroll
            for (int j = 0; j < 8; j++)
                pa[ks][j] = (short)PLDS(ks * 32 + lg * 8 + j, lc);
        }

        float* ud = upart + ((size_t)b * NCH + ch) * KK * DD;
        #pragma unroll
        for (int tt = 0; tt < 2; tt++) {
            int dt = w * 2 + tt;
            int dcol = dt * 16 + lc;
            f32x4 uacc = (f32x4){0.f, 0.f, 0.f, 0.f};
            #pragma unroll
            for (int ks = 0; ks < 4; ks++) {
                bf16x8 bf;
                #pragma unroll
                for (int j = 0; j < 8; j++) {
                    int n = ks * 32 + lg * 8 + j;
                    uint bo = ((uint)n * 256 + (uint)dcol * 2)
                              ^ (((uint)n & 7) << 4);
                    bf[j] = *(const short*)(xnlds + bo);
                }
                uacc = __builtin_amdgcn_mfma_f32_16x16x32_bf16(pa[ks], bf, uacc, 0, 0, 0);
            }
            #pragma unroll
            for (int r = 0; r < 4; r++) {
                int slot = lg * 4 + r;
                if (slot < KK)
                    ud[slot * DD + dt * 16 + lc] = uacc[r];
            }
        }
        if (last) {
            for (int i = t; i < NB * KK; i += 256) {
                int n = i / KK, s2 = i - n * KK;
                out_s[((size_t)b * NN + n0 + n) * KK + s2] = bf2f(PLDS(n, s2));
            }
        }

        gridbar(1 + 2 * it);

        // ================= phase B: slot update (bid < 80) =================
        if (bid < SLOTBLK) {
            int sb = bid / KK, kslot = bid % KK;
            // u partial reduce: 2 groups x 64 chunks
            {
                int j = t & 127, g = t >> 7;
                const float* up = upart + (size_t)sb * NCH * KK * DD + kslot * DD + j;
                float u = 0.f;
                for (int c = g * 64; c < (g + 1) * 64; c++) u += up[(size_t)c * KK * DD];
                upr_l[g * 128 + j] = u;
            }
            // denom: 128 chunks, 1/thread for t<128
            {
                float dsv = (t < 128) ?
                    dpart[((size_t)sb * NCH + t) * KK + kslot] : 0.f;
                #pragma unroll
                for (int o = 32; o > 0; o >>= 1) dsv += __shfl_xor(dsv, o);
                if ((l == 0)) red_l[4 + w] = dsv;
            }
            __syncthreads();

            float prev = 0.f;
            float denom = red_l[4] + red_l[5] + red_l[6] + red_l[7]
                          + (float)NN * ATT_EPS;
            if (t < DD) {
                float u = upr_l[t] + upr_l[128 + t];
                y_lds[t] = (u + ATT_EPS * sumx[sb * DD + t]) / denom;
                prev = slots[(sb * KK + kslot) * DD + t];
                p_lds[t] = prev;
            }
            __syncthreads();

            // gi/gh: 768 gate-columns over 256 threads (3 each)
            #pragma unroll
            for (int rep = 0; rep < 3; rep++) {
                int col768 = t + rep * 256;
                bool isGi = col768 < 384;
                int col = isGi ? col768 : col768 - 384;
                const float* Wt  = isGi ? Wvih : WhhT;
                const float* src = isGi ? y_lds : p_lds;
                float g0 = isGi ? bvih[col] : bhh[col];
                for (int d4 = 0; d4 < DD / 4; d4++) {
                    float4 v = *(const float4*)&src[d4 * 4];
                    const float* wp = Wt + (size_t)(d4 * 4) * 3 * DD + col;
                    g0 += v.x * wp[0] + v.y * wp[3 * DD] + v.z * wp[6 * DD] + v.w * wp[9 * DD];
                }
                if (isGi) gi_l[col] = g0; else gh_l[col] = g0;
            }
            __syncthreads();

            float snew = 0.f;
            if (t < DD) {
                float r = 1.f / (1.f + __expf(-(gi_l[t] + gh_l[t])));
                float z = 1.f / (1.f + __expf(-(gi_l[DD + t] + gh_l[DD + t])));
                float nn_ = tanhf(gi_l[2 * DD + t] + r * gh_l[2 * DD + t]);
                snew = (1.f - z) * nn_ + z * prev;
            }
            // LN(snew)
            {
                float s_ = (t < DD) ? snew : 0.f, sq_ = s_ * s_;
                #pragma unroll
                for (int o = 32; o > 0; o >>= 1) { s_ += __shfl_xor(s_, o); sq_ += __shfl_xor(sq_, o); }
                if (t < DD && (t & 63) == 0) { red_l[(t >> 6) * 2] = s_; red_l[(t >> 6) * 2 + 1] = sq_; }
            }
            __syncthreads();
            if (t < DD) {
                float mean = (red_l[0] + red_l[2]) * (1.0f / DD);
                float var  = (red_l[1] + red_l[3]) * (1.0f / DD) - mean * mean;
                float rstd = rsqrtf(var + LN_EPS);
                tmpb[t] = (snew - mean) * rstd * g_ff[t] + b_ff[t];
            }
            __syncthreads();
            // W1, 2-way split
            {
                int g = t >> 7, c = t & 127;
                float hp = 0.f;
                for (int d4 = g * 16; d4 < g * 16 + 16; d4++) {
                    float4 tv = *(const float4*)&tmpb[d4 * 4];
                    const float* wp = W1 + (size_t)(d4 * 4) * DD + c;
                    hp += tv.x * wp[0] + tv.y * wp[DD] + tv.z * wp[2 * DD] + tv.w * wp[3 * DD];
                }
                upr_l[g * 128 + c] = hp;
            }
            __syncthreads();
            if (t < DD) tmpb[t] = fmaxf(upr_l[t] + upr_l[128 + t] + b1[t], 0.f);
            __syncthreads();
            // W2, 2-way split
            {
                int g = t >> 7, c = t & 127;
                float hp = 0.f;
                for (int d4 = g * 16; d4 < g * 16 + 16; d4++) {
                    float4 tv = *(const float4*)&tmpb[d4 * 4];
                    const float* wp = W2 + (size_t)(d4 * 4) * DD + c;
                    hp += tv.x * wp[0] + tv.y * wp[DD] + tv.z * wp[2 * DD] + tv.w * wp[3 * DD];
                }
                upr_l[g * 128 + c] = hp;
            }
            __syncthreads();
            float o = 0.f;
            if (t < DD) {
                o = snew + b2[t] + upr_l[t] + upr_l[128 + t];
                slots[(sb * KK + kslot) * DD + t] = o;
            }
            // LN(o)
            {
                float s_ = (t < DD) ? o : 0.f, sq_ = s_ * s_;
                #pragma unroll
                for (int o2 = 32; o2 > 0; o2 >>= 1) { s_ += __shfl_xor(s_, o2); sq_ += __shfl_xor(sq_, o2); }
                if (t < DD && (t & 63) == 0) { red_l[(t >> 6) * 2] = s_; red_l[(t >> 6) * 2 + 1] = sq_; }
            }
            __syncthreads();
            if (t < DD) {
                float mean = (red_l[0] + red_l[2]) * (1.0f / DD);
                float var  = (red_l[1] + red_l[3]) * (1.0f / DD) - mean * mean;
                float rstd = rsqrtf(var + LN_EPS);
                tmpb[t] = (o - mean) * rstd * g_sl[t] + b_sl[t];
            }
            __syncthreads();
            // M, 2-way split
            {
                int g = t >> 7, c = t & 127;
                float hp = 0.f;
                for (int d4 = g * 16; d4 < g * 16 + 16; d4++) {
                    float4 tv = *(const float4*)&tmpb[d4 * 4];
                    const float* wp = M + (size_t)(d4 * 4) * DD + c;
                    hp += tv.x * wp[0] + tv.y * wp[DD] + tv.z * wp[2 * DD] + tv.w * wp[3 * DD];
                }
                upr_l[g * 128 + c] = hp;
            }
            __syncthreads();
            if (t < DD) {
                float qq = v0[t] + upr_l[t] + upr_l[128 + t];
                qp[(sb * KK + kslot) * DD + t] = SCALE * qq;
                if (last) {
                    out_nf[(sb * KK + kslot) * DD + t] = o;
                    if (t < KK) out_adj[(sb * KK + kslot) * KK + t] = 1.0f;
                }
            }
            {
                float cp = (t < DD) ? tmpb[t] * wqbk[t] : 0.f;
                #pragma unroll
                for (int o2 = 32; o2 > 0; o2 >>= 1) cp += __shfl_xor(cp, o2);
                if (t < 128 && (t & 63) == 0) red_l[4 + (t >> 6)] = cp;
            }
            __syncthreads();
            if (t == 0) qc0[sb * KK + kslot] = SCALE * (red_l[4] + red_l[5] + c1[0]);
        }

        if (!last) gridbar(2 + 2 * it);
    }
#undef QLDS
#undef PLDS
#undef FB
#undef p_lds
#undef tmpb
#undef y_lds
#undef gi_l
#undef gh_l
#undef upr_l
#undef red_l
}

// ------------------------------------------------------------------
extern "C" void kernel_launch(void* const* d_in, const int* in_sizes, int n_in,
                              void* d_out, int out_size, void* d_ws, size_t ws_size,
                              hipStream_t stream) {
    (void)in_sizes; (void)n_in; (void)out_size; (void)ws_size;
    const float* x        = (const float*)d_in[0];
    const float* noise    = (const float*)d_in[1];
    const float* mu       = (const float*)d_in[2];
    const float* logsigma = (const float*)d_in[3];
    const float* Wq  = (const float*)d_in[4];
    const float* bq  = (const float*)d_in[5];
    const float* Wk  = (const float*)d_in[6];
    const float* bk  = (const float*)d_in[7];
    const float* Wv  = (const float*)d_in[8];
    const float* bv  = (const float*)d_in[9];
    const float* Wih = (const float*)d_in[10];
    const float* Whh = (const float*)d_in[11];
    const float* bih = (const float*)d_in[12];
    const float* bhh = (const float*)d_in[13];
    const float* W1  = (const float*)d_in[14];
    const float* b1  = (const float*)d_in[15];
    const float* W2  = (const float*)d_in[16];
    const float* b2  = (const float*)d_in[17];
    const float* g_in = (const float*)d_in[18];
    const float* b_in = (const float*)d_in[19];
    const float* g_sl = (const float*)d_in[20];
    const float* b_sl = (const float*)d_in[21];
    const float* g_ff = (const float*)d_in[22];
    const float* b_ff = (const float*)d_in[23];

    float* w = (float*)d_ws;
    ushort* xn   = (ushort*)(w + OFF_XN);
    float* qp    = w + OFF_Q;
    float* qc0   = w + OFF_QC0;
    float* slots = w + OFF_SLOTS;
    float* upart = w + OFF_UPART;
    float* dpart = w + OFF_DPART;
    float* sxp   = w + OFF_SXP;
    float* sumx  = w + OFF_SUMX;
    float* WihT  = w + OFF_WIHT;
    float* WhhT  = w + OFF_WHHT;
    float* Wvih  = w + OFF_WVIH;
    float* bvih  = w + OFF_BVIH;
    float* Mw    = w + OFF_M;
    float* v0    = w + OFF_V0;
    float* wqbk  = w + OFF_WQBK;
    float* c1    = w + OFF_C1;
    int*   bar   = (int*)(w + OFF_BAR);

    float* out_nf  = (float*)d_out;                       // [B,K,D]
    float* out_adj = out_nf + BB * KK * DD;               // [B,K,K]
    float* out_s   = out_adj + BB * KK * KK;              // [B,N,K]

    k_zero<<<1, 256, 0, stream>>>(bar);
    k_prep<<<(PREP_TOTAL + 255) / 256, 256, 0, stream>>>(
        Wih, Whh, Wq, Wk, Wv, bih, bv, bq, bk,
        WihT, WhhT, Wvih, bvih, Mw, v0, wqbk, c1);
    k_ln<<<BB * LNCH, 256, 0, stream>>>(x, g_in, b_in, xn, sxp);
    k_sumx<<<BB, 512, 0, stream>>>(sxp, sumx);

    k_fused<<<NBLK, 256, 0, stream>>>(
        xn, noise, mu, logsigma, sumx,
        Wvih, bvih, WhhT, bhh, W1, b1, W2, b2,
        Mw, v0, wqbk, c1, g_ff, b_ff, g_sl, b_sl,
        slots, qp, qc0, upart, dpart, bar,
        out_nf, out_adj, out_s);
}

// Round 14
// 1209.391 us; speedup vs baseline: 13.0130x; 13.0130x over previous
//
#include <hip/hip_runtime.h>
#include <cstdint>

#define BB 8
#define NN 16384
#define DD 128
#define KK 10
#define N_ITERS 7
#define LN_EPS 1e-5f
#define ATT_EPS 1e-8f
#define SCALE 0.08838834764831845f   // D^-0.5

#define LNR 64                 // rows per ln block
#define LNCH (NN / LNR)        // 256 chunks per batch
#define NB 128                 // n per attn block
#define NCH (NN / NB)          // 128 chunks per batch
#define NBLK (BB * NCH)        // 1024 fused-grid blocks (= 4/CU exactly)
#define NGRP 64                // barrier groups
#define SLOTBLK (BB * KK)      // 80 blocks do slot phase

typedef __attribute__((ext_vector_type(8))) short bf16x8;
typedef __attribute__((ext_vector_type(4))) float f32x4;

__device__ inline ushort f2bf(float f) {
    uint u = __builtin_bit_cast(uint, f);
    u += 0x7FFFu + ((u >> 16) & 1u);
    return (ushort)(u >> 16);
}
__device__ inline float bf2f(ushort u) {
    return __builtin_bit_cast(float, ((uint)u) << 16);
}
// Coherent (LLC, L2-bypass) accesses for cross-XCD tensors — no cache inv.
__device__ inline float aldf(const float* p) {
    return __hip_atomic_load(p, __ATOMIC_RELAXED, __HIP_MEMORY_SCOPE_AGENT);
}
__device__ inline void astf(float* p, float v) {
    __hip_atomic_store(p, v, __ATOMIC_RELAXED, __HIP_MEMORY_SCOPE_AGENT);
}
// Release discipline without cache maintenance: drain outstanding VMEM
// (the astf stores are already LLC-coherent) before the arrival atomic.
__device__ inline void store_drain() {
    asm volatile("s_waitcnt vmcnt(0)" ::: "memory");
}

// ---- workspace layout (float units) ----
#define OFF_XN    ((size_t)0)
#define OFF_Q     (OFF_XN + (size_t)BB * NN * DD / 2)
#define OFF_QC0   (OFF_Q + (size_t)BB * KK * DD)
#define OFF_SLOTS (OFF_QC0 + 128)
#define OFF_UPART (OFF_SLOTS + (size_t)BB * KK * DD)
#define OFF_DPART (OFF_UPART + (size_t)BB * NCH * KK * DD)
#define OFF_SXP   (OFF_DPART + (size_t)BB * NCH * KK)
#define OFF_SUMX  (OFF_SXP + (size_t)BB * LNCH * DD)
#define OFF_WIHT  (OFF_SUMX + (size_t)BB * DD)
#define OFF_WHHT  (OFF_WIHT + (size_t)3 * DD * DD)
#define OFF_WVIH  (OFF_WHHT + (size_t)3 * DD * DD)
#define OFF_BVIH  (OFF_WVIH + (size_t)DD * 3 * DD)
#define OFF_M     (OFF_BVIH + (size_t)3 * DD)
#define OFF_V0    (OFF_M + (size_t)DD * DD)
#define OFF_WQBK  (OFF_V0 + (size_t)DD)
#define OFF_C1    (OFF_WQBK + (size_t)DD)
#define OFF_BAR   (OFF_C1 + 8)
#define BAR_INTS  (NGRP * 64 + 2)

// ------------------------------------------------------------------
__global__ void k_zero(int* __restrict__ bar) {
    int t = blockIdx.x * 256 + threadIdx.x;
    for (int i = t; i < BAR_INTS; i += 256) bar[i] = 0;
}

// ------------------------------------------------------------------
// Prep: transposes + folded weight products (one-time, fp32 exact).
__global__ void k_prep(const float* __restrict__ Wih, const float* __restrict__ Whh,
                       const float* __restrict__ Wq, const float* __restrict__ Wk,
                       const float* __restrict__ Wv,
                       const float* __restrict__ bih, const float* __restrict__ bv,
                       const float* __restrict__ bq, const float* __restrict__ bk,
                       float* __restrict__ WihT, float* __restrict__ WhhT,
                       float* __restrict__ Wvih, float* __restrict__ bvih,
                       float* __restrict__ M, float* __restrict__ v0,
                       float* __restrict__ wqbk, float* __restrict__ c1) {
    int idx = blockIdx.x * 256 + threadIdx.x;
    if (idx < 3 * DD * DD) {
        int d = idx / (3 * DD);
        int j = idx % (3 * DD);
        WihT[idx] = Wih[j * DD + d];
        WhhT[idx] = Whh[j * DD + d];
    } else if (idx < 2 * 3 * DD * DD) {
        int i = idx - 3 * DD * DD;
        int d = i / (3 * DD), t = i % (3 * DD);
        float s = 0.f;
        for (int e = 0; e < DD; e++) s += Wv[d * DD + e] * Wih[t * DD + e];
        Wvih[i] = s;
    } else if (idx < 2 * 3 * DD * DD + 3 * DD) {
        int t = idx - 2 * 3 * DD * DD;
        float s = bih[t];
        for (int e = 0; e < DD; e++) s += bv[e] * Wih[t * DD + e];
        bvih[t] = s;
    } else if (idx < 2 * 3 * DD * DD + 3 * DD + DD * DD) {
        int i = idx - (2 * 3 * DD * DD + 3 * DD);
        int d = i / DD, e = i % DD;
        float s = 0.f;
        for (int j = 0; j < DD; j++) s += Wq[d * DD + j] * Wk[e * DD + j];
        M[i] = s;
    } else if (idx < 2 * 3 * DD * DD + 3 * DD + DD * DD + DD) {
        int e = idx - (2 * 3 * DD * DD + 3 * DD + DD * DD);
        float s = 0.f;
        for (int j = 0; j < DD; j++) s += bq[j] * Wk[e * DD + j];
        v0[e] = s;
    } else if (idx < 2 * 3 * DD * DD + 3 * DD + DD * DD + 2 * DD) {
        int d = idx - (2 * 3 * DD * DD + 3 * DD + DD * DD + DD);
        float s = 0.f;
        for (int j = 0; j < DD; j++) s += Wq[d * DD + j] * bk[j];
        wqbk[d] = s;
    } else if (idx == 2 * 3 * DD * DD + 3 * DD + DD * DD + 2 * DD) {
        float s = 0.f;
        for (int j = 0; j < DD; j++) s += bq[j] * bk[j];
        c1[0] = s;
    }
}
#define PREP_TOTAL (2 * 3 * DD * DD + 3 * DD + DD * DD + 2 * DD + 1)

// ------------------------------------------------------------------
// Pure LayerNorm: x -> xn (row-major bf16) + sxp (partial column sums).
__global__ __launch_bounds__(256) void k_ln(
        const float* __restrict__ x,
        const float* __restrict__ g_in, const float* __restrict__ b_in,
        ushort* __restrict__ xn, float* __restrict__ sxp) {
    __shared__ ushort xt[LNR][136];

    int t = threadIdx.x, blk = blockIdx.x;
    int b = blk >> 8, ch = blk & (LNCH - 1);
    int n0 = ch * LNR;

    {
        int r = t >> 2, p = t & 3;
        const float4* xr = (const float4*)(x + ((size_t)(b * NN + n0 + r)) * DD + p * 32);
        float4 xv[8];
        float s = 0.f, sq = 0.f;
        #pragma unroll
        for (int i = 0; i < 8; i++) {
            xv[i] = xr[i];
            s  += xv[i].x + xv[i].y + xv[i].z + xv[i].w;
            sq += xv[i].x * xv[i].x + xv[i].y * xv[i].y +
                  xv[i].z * xv[i].z + xv[i].w * xv[i].w;
        }
        s += __shfl_xor(s, 1);  sq += __shfl_xor(sq, 1);
        s += __shfl_xor(s, 2);  sq += __shfl_xor(sq, 2);
        float mean = s * (1.0f / DD);
        float var  = sq * (1.0f / DD) - mean * mean;
        float rstd = rsqrtf(var + LN_EPS);
        ushort* xno = xn + ((size_t)(b * NN + n0 + r)) * DD + p * 32;
        #pragma unroll
        for (int i = 0; i < 8; i++) {
            int c0 = p * 32 + i * 4;
            ushort4 uv;
            uv.x = f2bf((xv[i].x - mean) * rstd * g_in[c0 + 0] + b_in[c0 + 0]);
            uv.y = f2bf((xv[i].y - mean) * rstd * g_in[c0 + 1] + b_in[c0 + 1]);
            uv.z = f2bf((xv[i].z - mean) * rstd * g_in[c0 + 2] + b_in[c0 + 2]);
            uv.w = f2bf((xv[i].w - mean) * rstd * g_in[c0 + 3] + b_in[c0 + 3]);
            *(ushort4*)&xt[r][c0] = uv;
            *(ushort4*)(xno + i * 4) = uv;
        }
    }
    __syncthreads();

    {
        int c = t >> 1, h = t & 1;
        float sx = 0.f;
        #pragma unroll
        for (int rr = 0; rr < 32; rr++) sx += bf2f(xt[h * 32 + rr][c]);
        sx += __shfl_xor(sx, 1);
        if (h == 0) sxp[((size_t)(b * LNCH + ch)) * DD + c] = sx;
    }
}

// ------------------------------------------------------------------
__global__ __launch_bounds__(512) void k_sumx(const float* __restrict__ sxp,
                                              float* __restrict__ sumx) {
    int b = blockIdx.x, t = threadIdx.x;
    int c = t & 127, g = t >> 7;
    __shared__ float part[4][DD];
    float s = 0.f;
    for (int cb = g * 64; cb < (g + 1) * 64; cb++)
        s += sxp[((size_t)(b * LNCH + cb)) * DD + c];
    part[g][c] = s;
    __syncthreads();
    if (t < DD) sumx[b * DD + t] = part[0][t] + part[1][t] + part[2][t] + part[3][t];
}

// ------------------------------------------------------------------
// Fused persistent kernel: init + 7 x (attn ; slot) with grid barriers.
// Cross-XCD data via relaxed agent atomics (LLC, no L2 invalidation).
__global__ __launch_bounds__(256, 4) void k_fused(
        const ushort* __restrict__ xn,
        const float* __restrict__ noise, const float* __restrict__ mu,
        const float* __restrict__ logsigma,
        const float* __restrict__ sumx,
        const float* __restrict__ Wvih, const float* __restrict__ bvih,
        const float* __restrict__ WhhT, const float* __restrict__ bhh,
        const float* __restrict__ W1, const float* __restrict__ b1,
        const float* __restrict__ W2, const float* __restrict__ b2,
        const float* __restrict__ M, const float* __restrict__ v0,
        const float* __restrict__ wqbk, const float* __restrict__ c1,
        const float* __restrict__ g_ff, const float* __restrict__ b_ff,
        const float* __restrict__ g_sl, const float* __restrict__ b_sl,
        float* __restrict__ slots, float* __restrict__ qp,
        float* __restrict__ qc0,
        float* __restrict__ upart, float* __restrict__ dpart,
        int* __restrict__ bar,
        float* __restrict__ out_nf, float* __restrict__ out_adj,
        float* __restrict__ out_s) {
    __shared__ char xnlds[32768];       // persistent [n(128)][d(128)] bf16, swizzled
    __shared__ char ubuf[5696];         // phase A: qpbuf[2176]u16 | phase B: floats
    __shared__ float red2[4][16];
    __shared__ float c0s[16];
#define QLDS(r, c) ((ushort*)ubuf)[(r) * 136 + (c)]
#define PLDS(n, k) ((ushort*)ubuf)[(n) * 17 + (k)]
#define FB ((float*)ubuf)
#define p_lds (FB)            /* [128] */
#define tmpb  (FB + 128)      /* [128] */
#define y_lds (FB + 256)      /* [128] */
#define gi_l  (FB + 384)      /* [384] */
#define gh_l  (FB + 768)      /* [384] */
#define upr_l (FB + 1152)     /* [2][128] */
#define red_l (FB + 1408)     /* [8] */

    int t = threadIdx.x;
    int bid = blockIdx.x;
    int b  = bid >> 7;
    int ch = bid & (NCH - 1);
    int n0 = ch * NB;
    int w = t >> 6, l = t & 63;
    int lc = l & 15, lg = l >> 4;
    int* gcnt = bar;                  // [NGRP*32] padded arrival counters
    int* grel = bar + NGRP * 32;      // [NGRP*32] padded per-group release
    int* tcnt = bar + NGRP * 64;
    int* rel  = bar + NGRP * 64 + 1;

    // ---- stage persistent xn tile (2048 x 16B chunks, swizzled) ----
    {
        const uint4* src = (const uint4*)(xn + ((size_t)(b * NN + n0)) * DD);
        #pragma unroll
        for (int i = 0; i < 8; i++) {
            int c = t + i * 256;
            uint4 v = src[c];
            int n = c >> 4;
            uint bo = ((uint)c * 16) ^ (((uint)n & 7) << 4);
            *(uint4*)(xnlds + bo) = v;
        }
    }

    // ---- init phase (bid < 80): slots, qp, qc0 ----
    if (bid < SLOTBLK) {
        int bk_ = bid;
        float sv = 0.f, sq = 0.f, s0 = 0.f;
        if (t < DD) {
            s0 = mu[t] + __expf(logsigma[t]) * noise[bk_ * DD + t];
            slots[bk_ * DD + t] = s0;
            sv = s0; sq = s0 * s0;
        }
        #pragma unroll
        for (int o = 32; o > 0; o >>= 1) { sv += __shfl_xor(sv, o); sq += __shfl_xor(sq, o); }
        if ((t & 63) == 0) { red_l[w * 2] = sv; red_l[w * 2 + 1] = sq; }
        __syncthreads();
        float mean = (red_l[0] + red_l[2]) * (1.0f / DD);
        float var  = (red_l[1] + red_l[3]) * (1.0f / DD) - mean * mean;
        float rstd = rsqrtf(var + LN_EPS);
        if (t < DD) tmpb[t] = (s0 - mean) * rstd * g_sl[t] + b_sl[t];
        __syncthreads();
        if (t < DD) {
            float qq = v0[t];
            for (int d = 0; d < DD; d++) qq += tmpb[d] * M[d * DD + t];
            astf(&qp[bk_ * DD + t], SCALE * qq);
        }
        {
            float cp = (t < DD) ? tmpb[t] * wqbk[t] : 0.f;
            #pragma unroll
            for (int o = 32; o > 0; o >>= 1) cp += __shfl_xor(cp, o);
            if (t < 128 && (t & 63) == 0) red_l[4 + w] = cp;
        }
        __syncthreads();
        if (t == 0) astf(&qc0[bk_], SCALE * (red_l[4] + red_l[5] + c1[0]));
    }

    // ---- grid barrier: store-drain + relaxed hierarchical spin ----
    auto gridbar = [&](int s) {
        __syncthreads();
        if (t == 0) {
            store_drain();
            int g = bid & (NGRP - 1);
            if (atomicAdd(&gcnt[g * 32], 1) == (s + 1) * (NBLK / NGRP) - 1) {
                if (atomicAdd(tcnt, 1) == (s + 1) * NGRP - 1) {
                    __hip_atomic_store(rel, s + 1, __ATOMIC_RELAXED,
                                       __HIP_MEMORY_SCOPE_AGENT);
                }
            }
            if (bid < NGRP) {
                while (__hip_atomic_load(rel, __ATOMIC_RELAXED,
                                         __HIP_MEMORY_SCOPE_AGENT) < s + 1)
                    __builtin_amdgcn_s_sleep(8);
                __hip_atomic_store(&grel[bid * 32], s + 1, __ATOMIC_RELAXED,
                                   __HIP_MEMORY_SCOPE_AGENT);
            } else {
                while (__hip_atomic_load(&grel[g * 32], __ATOMIC_RELAXED,
                                         __HIP_MEMORY_SCOPE_AGENT) < s + 1)
                    __builtin_amdgcn_s_sleep(8);
            }
        }
        __syncthreads();
    };

    gridbar(0);

    for (int it = 0; it < N_ITERS; it++) {
        int last = (it == N_ITERS - 1);
        // ================= phase A: attention =================
        for (int j = t; j < 16 * DD; j += 256) {
            int row = j >> 7, col = j & 127;
            float v = (row < KK) ? aldf(&qp[((size_t)b * KK + row) * DD + col]) : 0.f;
            QLDS(row, col) = f2bf(v);
        }
        if (t < 16) c0s[t] = (t < KK) ? aldf(&qc0[b * KK + t]) : 0.f;
        __syncthreads();

        bf16x8 qb[4];
        #pragma unroll
        for (int ks = 0; ks < 4; ks++)
            qb[ks] = *(const bf16x8*)&QLDS(lc, ks * 32 + lg * 8);
        float c0v = c0s[lc];
        __syncthreads();   // ubuf now reusable as plds

        float dsum = 0.f;
        bool valid = lc < KK;
        #pragma unroll
        for (int tt = 0; tt < 2; tt++) {
            int nt = w * 2 + tt;
            int nrow = nt * 16 + lc;
            f32x4 acc = (f32x4){0.f, 0.f, 0.f, 0.f};
            #pragma unroll
            for (int ks = 0; ks < 4; ks++) {
                uint bo = ((uint)nrow * 256 + (uint)(ks * 32 + lg * 8) * 2)
                          ^ (((uint)nrow & 7) << 4);
                bf16x8 a = *(const bf16x8*)(xnlds + bo);
                acc = __builtin_amdgcn_mfma_f32_16x16x32_bf16(a, qb[ks], acc, 0, 0, 0);
            }
            #pragma unroll
            for (int r = 0; r < 4; r++) {
                float v = acc[r] + c0v;
                float m = valid ? v : -3.0e38f;
                m = fmaxf(m, __shfl_xor(m, 1));
                m = fmaxf(m, __shfl_xor(m, 2));
                m = fmaxf(m, __shfl_xor(m, 4));
                m = fmaxf(m, __shfl_xor(m, 8));
                float e = valid ? __expf(v - m) : 0.f;
                float s = e;
                s += __shfl_xor(s, 1);
                s += __shfl_xor(s, 2);
                s += __shfl_xor(s, 4);
                s += __shfl_xor(s, 8);
                float p = e / s;
                dsum += p;
                PLDS(nt * 16 + lg * 4 + r, lc) = f2bf(p);
            }
        }
        dsum += __shfl_xor(dsum, 16);
        dsum += __shfl_xor(dsum, 32);
        if (l < 16) red2[w][l] = dsum;
        __syncthreads();
        if (t < KK)
            astf(&dpart[((size_t)b * NCH + ch) * KK + t],
                 red2[0][t] + red2[1][t] + red2[2][t] + red2[3][t]);

        bf16x8 pa[4];
        #pragma unroll
        for (int ks = 0; ks < 4; ks++) {
            #pragma unroll
            for (int j = 0; j < 8; j++)
                pa[ks][j] = (short)PLDS(ks * 32 + lg * 8 + j, lc);
        }

        float* ud = upart + ((size_t)b * NCH + ch) * KK * DD;
        #pragma unroll
        for (int tt = 0; tt < 2; tt++) {
            int dt = w * 2 + tt;
            int dcol = dt * 16 + lc;
            f32x4 uacc = (f32x4){0.f, 0.f, 0.f, 0.f};
            #pragma unroll
            for (int ks = 0; ks < 4; ks++) {
                bf16x8 bf;
                #pragma unroll
                for (int j = 0; j < 8; j++) {
                    int n = ks * 32 + lg * 8 + j;
                    uint bo = ((uint)n * 256 + (uint)dcol * 2)
                              ^ (((uint)n & 7) << 4);
                    bf[j] = *(const short*)(xnlds + bo);
                }
                uacc = __builtin_amdgcn_mfma_f32_16x16x32_bf16(pa[ks], bf, uacc, 0, 0, 0);
            }
            #pragma unroll
            for (int r = 0; r < 4; r++) {
                int slot = lg * 4 + r;
                if (slot < KK)
                    astf(&ud[slot * DD + dt * 16 + lc], uacc[r]);
            }
        }
        if (last) {
            for (int i = t; i < NB * KK; i += 256) {
                int n = i / KK, s2 = i - n * KK;
                out_s[((size_t)b * NN + n0 + n) * KK + s2] = bf2f(PLDS(n, s2));
            }
        }

        gridbar(1 + 2 * it);

        // ================= phase B: slot update (bid < 80) =================
        if (bid < SLOTBLK) {
            int sb = bid / KK, kslot = bid % KK;
            // u partial reduce: 2 groups x 64 chunks (coherent loads)
            {
                int j = t & 127, g = t >> 7;
                const float* up = upart + (size_t)sb * NCH * KK * DD + kslot * DD + j;
                float u = 0.f;
                for (int c = g * 64; c < (g + 1) * 64; c++)
                    u += aldf(&up[(size_t)c * KK * DD]);
                upr_l[g * 128 + j] = u;
            }
            // denom: 128 chunks, 1/thread for t<128
            {
                float dsv = (t < 128) ?
                    aldf(&dpart[((size_t)sb * NCH + t) * KK + kslot]) : 0.f;
                #pragma unroll
                for (int o = 32; o > 0; o >>= 1) dsv += __shfl_xor(dsv, o);
                if (l == 0) red_l[4 + w] = dsv;
            }
            __syncthreads();

            float prev = 0.f;
            float denom = red_l[4] + red_l[5] + red_l[6] + red_l[7]
                          + (float)NN * ATT_EPS;
            if (t < DD) {
                float u = upr_l[t] + upr_l[128 + t];
                y_lds[t] = (u + ATT_EPS * sumx[sb * DD + t]) / denom;
                prev = slots[(sb * KK + kslot) * DD + t];
                p_lds[t] = prev;
            }
            __syncthreads();

            // gi/gh: 768 gate-columns over 256 threads (3 each)
            #pragma unroll
            for (int rep = 0; rep < 3; rep++) {
                int col768 = t + rep * 256;
                bool isGi = col768 < 384;
                int col = isGi ? col768 : col768 - 384;
                const float* Wt  = isGi ? Wvih : WhhT;
                const float* src = isGi ? y_lds : p_lds;
                float g0 = isGi ? bvih[col] : bhh[col];
                for (int d4 = 0; d4 < DD / 4; d4++) {
                    float4 v = *(const float4*)&src[d4 * 4];
                    const float* wp = Wt + (size_t)(d4 * 4) * 3 * DD + col;
                    g0 += v.x * wp[0] + v.y * wp[3 * DD] + v.z * wp[6 * DD] + v.w * wp[9 * DD];
                }
                if (isGi) gi_l[col] = g0; else gh_l[col] = g0;
            }
            __syncthreads();

            float snew = 0.f;
            if (t < DD) {
                float r = 1.f / (1.f + __expf(-(gi_l[t] + gh_l[t])));
                float z = 1.f / (1.f + __expf(-(gi_l[DD + t] + gh_l[DD + t])));
                float nn_ = tanhf(gi_l[2 * DD + t] + r * gh_l[2 * DD + t]);
                snew = (1.f - z) * nn_ + z * prev;
            }
            // LN(snew)
            {
                float s_ = (t < DD) ? snew : 0.f, sq_ = s_ * s_;
                #pragma unroll
                for (int o = 32; o > 0; o >>= 1) { s_ += __shfl_xor(s_, o); sq_ += __shfl_xor(sq_, o); }
                if (t < DD && (t & 63) == 0) { red_l[(t >> 6) * 2] = s_; red_l[(t >> 6) * 2 + 1] = sq_; }
            }
            __syncthreads();
            if (t < DD) {
                float mean = (red_l[0] + red_l[2]) * (1.0f / DD);
                float var  = (red_l[1] + red_l[3]) * (1.0f / DD) - mean * mean;
                float rstd = rsqrtf(var + LN_EPS);
                tmpb[t] = (snew - mean) * rstd * g_ff[t] + b_ff[t];
            }
            __syncthreads();
            // W1, 2-way split
            {
                int g = t >> 7, c = t & 127;
                float hp = 0.f;
                for (int d4 = g * 16; d4 < g * 16 + 16; d4++) {
                    float4 tv = *(const float4*)&tmpb[d4 * 4];
                    const float* wp = W1 + (size_t)(d4 * 4) * DD + c;
                    hp += tv.x * wp[0] + tv.y * wp[DD] + tv.z * wp[2 * DD] + tv.w * wp[3 * DD];
                }
                upr_l[g * 128 + c] = hp;
            }
            __syncthreads();
            if (t < DD) tmpb[t] = fmaxf(upr_l[t] + upr_l[128 + t] + b1[t], 0.f);
            __syncthreads();
            // W2, 2-way split
            {
                int g = t >> 7, c = t & 127;
                float hp = 0.f;
                for (int d4 = g * 16; d4 < g * 16 + 16; d4++) {
                    float4 tv = *(const float4*)&tmpb[d4 * 4];
                    const float* wp = W2 + (size_t)(d4 * 4) * DD + c;
                    hp += tv.x * wp[0] + tv.y * wp[DD] + tv.z * wp[2 * DD] + tv.w * wp[3 * DD];
                }
                upr_l[g * 128 + c] = hp;
            }
            __syncthreads();
            float o = 0.f;
            if (t < DD) {
                o = snew + b2[t] + upr_l[t] + upr_l[128 + t];
                slots[(sb * KK + kslot) * DD + t] = o;
            }
            // LN(o)
            {
                float s_ = (t < DD) ? o : 0.f, sq_ = s_ * s_;
                #pragma unroll
                for (int o2 = 32; o2 > 0; o2 >>= 1) { s_ += __shfl_xor(s_, o2); sq_ += __shfl_xor(sq_, o2); }
                if (t < DD && (t & 63) == 0) { red_l[(t >> 6) * 2] = s_; red_l[(t >> 6) * 2 + 1] = sq_; }
            }
            __syncthreads();
            if (t < DD) {
                float mean = (red_l[0] + red_l[2]) * (1.0f / DD);
                float var  = (red_l[1] + red_l[3]) * (1.0f / DD) - mean * mean;
                float rstd = rsqrtf(var + LN_EPS);
                tmpb[t] = (o - mean) * rstd * g_sl[t] + b_sl[t];
            }
            __syncthreads();
            // M, 2-way split
            {
                int g = t >> 7, c = t & 127;
                float hp = 0.f;
                for (int d4 = g * 16; d4 < g * 16 + 16; d4++) {
                    float4 tv = *(const float4*)&tmpb[d4 * 4];
                    const float* wp = M + (size_t)(d4 * 4) * DD + c;
                    hp += tv.x * wp[0] + tv.y * wp[DD] + tv.z * wp[2 * DD] + tv.w * wp[3 * DD];
                }
                upr_l[g * 128 + c] = hp;
            }
            __syncthreads();
            if (t < DD) {
                float qq = v0[t] + upr_l[t] + upr_l[128 + t];
                astf(&qp[(sb * KK + kslot) * DD + t], SCALE * qq);
                if (last) {
                    out_nf[(sb * KK + kslot) * DD + t] = o;
                    if (t < KK) out_adj[(sb * KK + kslot) * KK + t] = 1.0f;
                }
            }
            {
                float cp = (t < DD) ? tmpb[t] * wqbk[t] : 0.f;
                #pragma unroll
                for (int o2 = 32; o2 > 0; o2 >>= 1) cp += __shfl_xor(cp, o2);
                if (t < 128 && (t & 63) == 0) red_l[4 + (t >> 6)] = cp;
            }
            __syncthreads();
            if (t == 0) astf(&qc0[sb * KK + kslot],
                             SCALE * (red_l[4] + red_l[5] + c1[0]));
        }

        if (!last) gridbar(2 + 2 * it);
    }
#undef QLDS
#undef PLDS
#undef FB
#undef p_lds
#undef tmpb
#undef y_lds
#undef gi_l
#undef gh_l
#undef upr_l
#undef red_l
}

// ------------------------------------------------------------------
extern "C" void kernel_launch(void* const* d_in, const int* in_sizes, int n_in,
                              void* d_out, int out_size, void* d_ws, size_t ws_size,
                              hipStream_t stream) {
    (void)in_sizes; (void)n_in; (void)out_size; (void)ws_size;
    const float* x        = (const float*)d_in[0];
    const float* noise    = (const float*)d_in[1];
    const float* mu       = (const float*)d_in[2];
    const float* logsigma = (const float*)d_in[3];
    const float* Wq  = (const float*)d_in[4];
    const float* bq  = (const float*)d_in[5];
    const float* Wk  = (const float*)d_in[6];
    const float* bk  = (const float*)d_in[7];
    const float* Wv  = (const float*)d_in[8];
    const float* bv  = (const float*)d_in[9];
    const float* Wih = (const float*)d_in[10];
    const float* Whh = (const float*)d_in[11];
    const float* bih = (const float*)d_in[12];
    const float* bhh = (const float*)d_in[13];
    const float* W1  = (const float*)d_in[14];
    const float* b1  = (const float*)d_in[15];
    const float* W2  = (const float*)d_in[16];
    const float* b2  = (const float*)d_in[17];
    const float* g_in = (const float*)d_in[18];
    const float* b_in = (const float*)d_in[19];
    const float* g_sl = (const float*)d_in[20];
    const float* b_sl = (const float*)d_in[21];
    const float* g_ff = (const float*)d_in[22];
    const float* b_ff = (const float*)d_in[23];

    float* w = (float*)d_ws;
    ushort* xn   = (ushort*)(w + OFF_XN);
    float* qp    = w + OFF_Q;
    float* qc0   = w + OFF_QC0;
    float* slots = w + OFF_SLOTS;
    float* upart = w + OFF_UPART;
    float* dpart = w + OFF_DPART;
    float* sxp   = w + OFF_SXP;
    float* sumx  = w + OFF_SUMX;
    float* WihT  = w + OFF_WIHT;
    float* WhhT  = w + OFF_WHHT;
    float* Wvih  = w + OFF_WVIH;
    float* bvih  = w + OFF_BVIH;
    float* Mw    = w + OFF_M;
    float* v0    = w + OFF_V0;
    float* wqbk  = w + OFF_WQBK;
    float* c1    = w + OFF_C1;
    int*   bar   = (int*)(w + OFF_BAR);

    float* out_nf  = (float*)d_out;                       // [B,K,D]
    float* out_adj = out_nf + BB * KK * DD;               // [B,K,K]
    float* out_s   = out_adj + BB * KK * KK;              // [B,N,K]

    k_zero<<<1, 256, 0, stream>>>(bar);
    k_prep<<<(PREP_TOTAL + 255) / 256, 256, 0, stream>>>(
        Wih, Whh, Wq, Wk, Wv, bih, bv, bq, bk,
        WihT, WhhT, Wvih, bvih, Mw, v0, wqbk, c1);
    k_ln<<<BB * LNCH, 256, 0, stream>>>(x, g_in, b_in, xn, sxp);
    k_sumx<<<BB, 512, 0, stream>>>(sxp, sumx);

    k_fused<<<NBLK, 256, 0, stream>>>(
        xn, noise, mu, logsigma, sumx,
        Wvih, bvih, WhhT, bhh, W1, b1, W2, b2,
        Mw, v0, wqbk, c1, g_ff, b_ff, g_sl, b_sl,
        slots, qp, qc0, upart, dpart, bar,
        out_nf, out_adj, out_s);
}

// Round 17
// 249.591 us; speedup vs baseline: 63.0542x; 4.8455x over previous
//
#include <hip/hip_runtime.h>
#include <cstdint>

#define BB 8
#define NN 16384
#define DD 128
#define KK 10
#define N_ITERS 7
#define LN_EPS 1e-5f
#define ATT_EPS 1e-8f
#define SCALE 0.08838834764831845f   // D^-0.5

#define LNR 64                 // rows per ln block
#define LNCH (NN / LNR)        // 256 chunks per batch
#define NB 256                 // n per attn block (2 sub-tiles of 128)
#define NCH (NN / NB)          // 64 chunks per batch

typedef __attribute__((ext_vector_type(8))) short bf16x8;
typedef __attribute__((ext_vector_type(4))) float f32x4;

__device__ inline ushort f2bf(float f) {
    uint u = __builtin_bit_cast(uint, f);
    u += 0x7FFFu + ((u >> 16) & 1u);
    return (ushort)(u >> 16);
}
__device__ inline float bf2f(ushort u) {
    return __builtin_bit_cast(float, ((uint)u) << 16);
}

// ---- workspace layout (float units) ----
#define OFF_XN    ((size_t)0)
#define OFF_Q     (OFF_XN + (size_t)BB * NN * DD / 2)
#define OFF_QC0   (OFF_Q + (size_t)BB * KK * DD)
#define OFF_SLOTS (OFF_QC0 + 128)
#define OFF_UPART (OFF_SLOTS + (size_t)BB * KK * DD)
#define OFF_DPART (OFF_UPART + (size_t)BB * NCH * KK * DD)
#define OFF_SXP   (OFF_DPART + (size_t)BB * NCH * KK)
#define OFF_SUMX  (OFF_SXP + (size_t)BB * LNCH * DD)
#define OFF_WIHT  (OFF_SUMX + (size_t)BB * DD)
#define OFF_WHHT  (OFF_WIHT + (size_t)3 * DD * DD)
#define OFF_WVIH  (OFF_WHHT + (size_t)3 * DD * DD)
#define OFF_BVIH  (OFF_WVIH + (size_t)DD * 3 * DD)
#define OFF_M     (OFF_BVIH + (size_t)3 * DD)
#define OFF_V0    (OFF_M + (size_t)DD * DD)
#define OFF_WQBK  (OFF_V0 + (size_t)DD)
#define OFF_C1    (OFF_WQBK + (size_t)DD)

// ------------------------------------------------------------------
// Prep: transposes + folded weight products (one-time, fp32 exact).
__global__ void k_prep(const float* __restrict__ Wih, const float* __restrict__ Whh,
                       const float* __restrict__ Wq, const float* __restrict__ Wk,
                       const float* __restrict__ Wv,
                       const float* __restrict__ bih, const float* __restrict__ bv,
                       const float* __restrict__ bq, const float* __restrict__ bk,
                       float* __restrict__ WihT, float* __restrict__ WhhT,
                       float* __restrict__ Wvih, float* __restrict__ bvih,
                       float* __restrict__ M, float* __restrict__ v0,
                       float* __restrict__ wqbk, float* __restrict__ c1) {
    int idx = blockIdx.x * 256 + threadIdx.x;
    if (idx < 3 * DD * DD) {
        int d = idx / (3 * DD);
        int j = idx % (3 * DD);
        WihT[idx] = Wih[j * DD + d];
        WhhT[idx] = Whh[j * DD + d];
    } else if (idx < 2 * 3 * DD * DD) {
        int i = idx - 3 * DD * DD;
        int d = i / (3 * DD), t = i % (3 * DD);
        float s = 0.f;
        for (int e = 0; e < DD; e++) s += Wv[d * DD + e] * Wih[t * DD + e];
        Wvih[i] = s;
    } else if (idx < 2 * 3 * DD * DD + 3 * DD) {
        int t = idx - 2 * 3 * DD * DD;
        float s = bih[t];
        for (int e = 0; e < DD; e++) s += bv[e] * Wih[t * DD + e];
        bvih[t] = s;
    } else if (idx < 2 * 3 * DD * DD + 3 * DD + DD * DD) {
        int i = idx - (2 * 3 * DD * DD + 3 * DD);
        int d = i / DD, e = i % DD;
        float s = 0.f;
        for (int j = 0; j < DD; j++) s += Wq[d * DD + j] * Wk[e * DD + j];
        M[i] = s;
    } else if (idx < 2 * 3 * DD * DD + 3 * DD + DD * DD + DD) {
        int e = idx - (2 * 3 * DD * DD + 3 * DD + DD * DD);
        float s = 0.f;
        for (int j = 0; j < DD; j++) s += bq[j] * Wk[e * DD + j];
        v0[e] = s;
    } else if (idx < 2 * 3 * DD * DD + 3 * DD + DD * DD + 2 * DD) {
        int d = idx - (2 * 3 * DD * DD + 3 * DD + DD * DD + DD);
        float s = 0.f;
        for (int j = 0; j < DD; j++) s += Wq[d * DD + j] * bk[j];
        wqbk[d] = s;
    } else if (idx == 2 * 3 * DD * DD + 3 * DD + DD * DD + 2 * DD) {
        float s = 0.f;
        for (int j = 0; j < DD; j++) s += bq[j] * bk[j];
        c1[0] = s;
    }
}
#define PREP_TOTAL (2 * 3 * DD * DD + 3 * DD + DD * DD + 2 * DD + 1)

// ------------------------------------------------------------------
// Pure LayerNorm: x -> xn (row-major bf16) + sxp (partial column sums).
__global__ __launch_bounds__(256) void k_ln(
        const float* __restrict__ x,
        const float* __restrict__ g_in, const float* __restrict__ b_in,
        ushort* __restrict__ xn, float* __restrict__ sxp) {
    __shared__ ushort xt[LNR][136];

    int t = threadIdx.x, blk = blockIdx.x;
    int b = blk >> 8, ch = blk & (LNCH - 1);
    int n0 = ch * LNR;

    {
        int r = t >> 2, p = t & 3;
        const float4* xr = (const float4*)(x + ((size_t)(b * NN + n0 + r)) * DD + p * 32);
        float4 xv[8];
        float s = 0.f, sq = 0.f;
        #pragma unroll
        for (int i = 0; i < 8; i++) {
            xv[i] = xr[i];
            s  += xv[i].x + xv[i].y + xv[i].z + xv[i].w;
            sq += xv[i].x * xv[i].x + xv[i].y * xv[i].y +
                  xv[i].z * xv[i].z + xv[i].w * xv[i].w;
        }
        s += __shfl_xor(s, 1);  sq += __shfl_xor(sq, 1);
        s += __shfl_xor(s, 2);  sq += __shfl_xor(sq, 2);
        float mean = s * (1.0f / DD);
        float var  = sq * (1.0f / DD) - mean * mean;
        float rstd = rsqrtf(var + LN_EPS);
        ushort* xno = xn + ((size_t)(b * NN + n0 + r)) * DD + p * 32;
        #pragma unroll
        for (int i = 0; i < 8; i++) {
            int c0 = p * 32 + i * 4;
            ushort4 uv;
            uv.x = f2bf((xv[i].x - mean) * rstd * g_in[c0 + 0] + b_in[c0 + 0]);
            uv.y = f2bf((xv[i].y - mean) * rstd * g_in[c0 + 1] + b_in[c0 + 1]);
            uv.z = f2bf((xv[i].z - mean) * rstd * g_in[c0 + 2] + b_in[c0 + 2]);
            uv.w = f2bf((xv[i].w - mean) * rstd * g_in[c0 + 3] + b_in[c0 + 3]);
            *(ushort4*)&xt[r][c0] = uv;
            *(ushort4*)(xno + i * 4) = uv;
        }
    }
    __syncthreads();

    {
        int c = t >> 1, h = t & 1;
        float sx = 0.f;
        #pragma unroll
        for (int rr = 0; rr < 32; rr++) sx += bf2f(xt[h * 32 + rr][c]);
        sx += __shfl_xor(sx, 1);
        if (h == 0) sxp[((size_t)(b * LNCH + ch)) * DD + c] = sx;
    }
}

// ------------------------------------------------------------------
__global__ __launch_bounds__(512) void k_sumx(const float* __restrict__ sxp,
                                              float* __restrict__ sumx) {
    int b = blockIdx.x, t = threadIdx.x;
    int c = t & 127, g = t >> 7;
    __shared__ float part[4][DD];
    float s = 0.f;
    for (int cb = g * 64; cb < (g + 1) * 64; cb++)
        s += sxp[((size_t)(b * LNCH + cb)) * DD + c];
    part[g][c] = s;
    __syncthreads();
    if (t < DD) sumx[b * DD + t] = part[0][t] + part[1][t] + part[2][t] + part[3][t];
}

// ------------------------------------------------------------------
__device__ inline void block_stats(float v, float& mean, float& rstd, float* red) {
    float s = v, sq = v * v;
    #pragma unroll
    for (int o = 32; o > 0; o >>= 1) {
        s  += __shfl_down(s, o, 64);
        sq += __shfl_down(sq, o, 64);
    }
    int lane = threadIdx.x & 63, w = threadIdx.x >> 6;
    if (lane == 0) { red[w * 2] = s; red[w * 2 + 1] = sq; }
    __syncthreads();
    float S = red[0] + red[2], SQ = red[1] + red[3];
    mean = S * (1.0f / DD);
    float var = SQ * (1.0f / DD) - mean * mean;
    rstd = rsqrtf(var + LN_EPS);
    __syncthreads();
}

// ------------------------------------------------------------------
__global__ __launch_bounds__(128) void k_init(
        const float* __restrict__ noise, const float* __restrict__ mu,
        const float* __restrict__ logsigma,
        const float* __restrict__ M, const float* __restrict__ v0,
        const float* __restrict__ wqbk, const float* __restrict__ c1,
        const float* __restrict__ g_sl, const float* __restrict__ b_sl,
        float* __restrict__ slots, float* __restrict__ qp,
        float* __restrict__ qc0) {
    int bk_ = blockIdx.x;
    int j = threadIdx.x;
    __shared__ float red[4];
    __shared__ float tmp[DD];
    float s = mu[j] + __expf(logsigma[j]) * noise[bk_ * DD + j];
    slots[bk_ * DD + j] = s;
    float m, rs;
    block_stats(s, m, rs, red);
    tmp[j] = (s - m) * rs * g_sl[j] + b_sl[j];
    __syncthreads();
    float qq = v0[j];
    for (int d = 0; d < DD; d++) qq += tmp[d] * M[d * DD + j];
    qp[bk_ * DD + j] = SCALE * qq;
    float cp = tmp[j] * wqbk[j];
    #pragma unroll
    for (int o = 32; o > 0; o >>= 1) cp += __shfl_xor(cp, o);
    if ((j & 63) == 0) red[j >> 6] = cp;
    __syncthreads();
    if (j == 0) qc0[bk_] = SCALE * (red[0] + red[1] + c1[0]);
}

// ------------------------------------------------------------------
// MFMA attention iteration, NB=256 per block in 2 sub-tiles of 128.
// PV accumulates across sub-tiles in registers; xlds/plds reused.
__global__ __launch_bounds__(256) void k_attn(
        const ushort* __restrict__ xn,
        const float* __restrict__ qp, const float* __restrict__ qc0,
        float* __restrict__ upart, float* __restrict__ dpart,
        float* __restrict__ out_s, int last) {
    __shared__ ushort qpbuf[2176];      // qlds [16][136] then plds [128][17]
    __shared__ ushort xlds[DD * 136];   // [d][n(128)] pad, XOR-swizzled 16B slots
    __shared__ float red2[4][16];
    __shared__ float c0s[16];
#define QLDS(r, c) qpbuf[(r) * 136 + (c)]
#define PLDS(n, k) qpbuf[(n) * 17 + (k)]

    int t = threadIdx.x;
    int blk = blockIdx.x;
    int b  = blk >> 6;
    int ch = blk & (NCH - 1);
    int n0 = ch * NB;
    int w = t >> 6, l = t & 63;
    int lc = l & 15, lg = l >> 4;

    for (int j = t; j < 16 * DD; j += 256) {
        int row = j >> 7, col = j & 127;
        float v = (row < KK) ? qp[((size_t)b * KK + row) * DD + col] : 0.f;
        QLDS(row, col) = f2bf(v);
    }
    if (t < 16) c0s[t] = (t < KK) ? qc0[b * KK + t] : 0.f;
    __syncthreads();

    bf16x8 qb[4];
    #pragma unroll
    for (int ks = 0; ks < 4; ks++)
        qb[ks] = *(const bf16x8*)&QLDS(lc, ks * 32 + lg * 8);
    float c0v = c0s[lc];
    __syncthreads();   // qpbuf now reusable as plds

    f32x4 uacc[2];
    uacc[0] = (f32x4){0.f, 0.f, 0.f, 0.f};
    uacc[1] = (f32x4){0.f, 0.f, 0.f, 0.f};
    float dsum = 0.f;
    bool valid = lc < KK;

    for (int sub = 0; sub < 2; sub++) {
        int nbase = n0 + sub * 128;
        #pragma unroll
        for (int tt = 0; tt < 2; tt++) {
            int nt = w * 2 + tt;    // n-tile 0..7 within sub
            int nrow = nt * 16 + lc;
            const ushort* kb = xn + ((size_t)(b * NN + nbase + nrow)) * DD + lg * 8;
            f32x4 acc = (f32x4){0.f, 0.f, 0.f, 0.f};
            #pragma unroll
            for (int ks = 0; ks < 4; ks++) {
                bf16x8 a = *(const bf16x8*)(kb + ks * 32);   // 16B coalesced
                int dbase = ks * 32 + lg * 8;
                uint swz = (uint)(lg << 4);
                #pragma unroll
                for (int j = 0; j < 8; j++) {
                    uint byteoff = ((uint)(dbase + j) * 272 + (uint)nrow * 2) ^ swz;
                    *(ushort*)((char*)xlds + byteoff) = (ushort)a[j];
                }
                acc = __builtin_amdgcn_mfma_f32_16x16x32_bf16(a, qb[ks], acc, 0, 0, 0);
            }
            #pragma unroll
            for (int r = 0; r < 4; r++) {
                float v = acc[r] + c0v;
                float m = valid ? v : -3.0e38f;
                m = fmaxf(m, __shfl_xor(m, 1));
                m = fmaxf(m, __shfl_xor(m, 2));
                m = fmaxf(m, __shfl_xor(m, 4));
                m = fmaxf(m, __shfl_xor(m, 8));
                float e = valid ? __expf(v - m) : 0.f;
                float s = e;
                s += __shfl_xor(s, 1);
                s += __shfl_xor(s, 2);
                s += __shfl_xor(s, 4);
                s += __shfl_xor(s, 8);
                float p = e / s;
                dsum += p;
                PLDS(nt * 16 + lg * 4 + r, lc) = f2bf(p);
            }
        }
        __syncthreads();    // plds + xlds ready

        bf16x8 pa[4];
        #pragma unroll
        for (int ks = 0; ks < 4; ks++) {
            #pragma unroll
            for (int j = 0; j < 8; j++)
                pa[ks][j] = (short)PLDS(ks * 32 + lg * 8 + j, lc);
        }
        #pragma unroll
        for (int tt = 0; tt < 2; tt++) {
            int dt = w * 2 + tt;
            int drow = dt * 16 + lc;
            uint rswz = (uint)(((drow >> 3) & 3) << 4);
            #pragma unroll
            for (int ks = 0; ks < 4; ks++) {
                uint byteoff = ((uint)drow * 272 + (uint)(ks * 32 + lg * 8) * 2) ^ rswz;
                bf16x8 bf = *(const bf16x8*)((const char*)xlds + byteoff);
                uacc[tt] = __builtin_amdgcn_mfma_f32_16x16x32_bf16(pa[ks], bf, uacc[tt], 0, 0, 0);
            }
        }
        if (last) {
            for (int i = t; i < 128 * KK; i += 256) {
                int n = i / KK, s2 = i - n * KK;
                out_s[((size_t)b * NN + nbase + n) * KK + s2] = bf2f(PLDS(n, s2));
            }
        }
        __syncthreads();    // before next sub overwrites plds/xlds
    }

    dsum += __shfl_xor(dsum, 16);
    dsum += __shfl_xor(dsum, 32);
    if (l < 16) red2[w][l] = dsum;
    __syncthreads();
    if (t < KK)
        dpart[((size_t)b * NCH + ch) * KK + t] =
            red2[0][t] + red2[1][t] + red2[2][t] + red2[3][t];

    float* ud = upart + ((size_t)b * NCH + ch) * KK * DD;
    #pragma unroll
    for (int tt = 0; tt < 2; tt++) {
        int dt = w * 2 + tt;
        #pragma unroll
        for (int r = 0; r < 4; r++) {
            int slot = lg * 4 + r;
            if (slot < KK)
                ud[slot * DD + dt * 16 + lc] = uacc[tt][r];
        }
    }
#undef QLDS
#undef PLDS
}

// ------------------------------------------------------------------
// 768 threads: split-parallel matvecs, short serial chains.
__global__ __launch_bounds__(768) void k_slot(
        const float* __restrict__ upart, const float* __restrict__ dpart,
        const float* __restrict__ sumx,
        const float* __restrict__ Wvih, const float* __restrict__ bvih,
        const float* __restrict__ WhhT, const float* __restrict__ bhh,
        const float* __restrict__ W1, const float* __restrict__ b1,
        const float* __restrict__ W2, const float* __restrict__ b2,
        const float* __restrict__ M, const float* __restrict__ v0,
        const float* __restrict__ wqbk, const float* __restrict__ c1,
        const float* __restrict__ g_ff, const float* __restrict__ b_ff,
        const float* __restrict__ g_sl, const float* __restrict__ b_sl,
        float* __restrict__ slots, float* __restrict__ qp,
        float* __restrict__ qc0,
        float* __restrict__ out_nf, float* __restrict__ out_adj, int last) {
    int blk = blockIdx.x;
    int b = blk / KK, kslot = blk % KK;
    int t = threadIdx.x;
    __shared__ float p_lds[DD], tmp[DD], y_lds[DD];
    __shared__ float gi_lds[3 * DD], gh_lds[3 * DD];
    __shared__ float upr[6][DD];
    __shared__ float pp[4][DD];
    __shared__ float red[8];

    // --- u partial reduce over NCH=64 chunks, 6 groups ---
    {
        int j = t & 127, g = t >> 7;          // g = 0..5
        int c0 = (g * NCH) / 6, cend = ((g + 1) * NCH) / 6;
        const float* up = upart + (size_t)b * NCH * KK * DD + kslot * DD + j;
        float u = 0.f;
        for (int c = c0; c < cend; c++) u += up[(size_t)c * KK * DD];
        upr[g][j] = u;
    }
    // --- denom: 64 chunks, one per thread, shfl reduce ---
    {
        float dsv = 0.f;
        if (t < 64) dsv = dpart[((size_t)b * NCH + t) * KK + kslot];
        #pragma unroll
        for (int o = 32; o > 0; o >>= 1) dsv += __shfl_xor(dsv, o);
        if (t == 0) red[6] = dsv + (float)NN * ATT_EPS;
    }
    __syncthreads();

    float prev = 0.f;
    if (t < DD) {
        float u = upr[0][t] + upr[1][t] + upr[2][t] +
                  upr[3][t] + upr[4][t] + upr[5][t];
        y_lds[t] = (u + ATT_EPS * sumx[b * DD + t]) / red[6];   // Yw
        prev = slots[(b * KK + kslot) * DD + t];
        p_lds[t] = prev;
    }
    __syncthreads();

    // --- gi/gh: 768 threads, one gate-column each ---
    {
        bool isGi = t < 384;
        int col = isGi ? t : t - 384;
        const float* Wt  = isGi ? Wvih : WhhT;
        const float* src = isGi ? y_lds : p_lds;
        float g0 = isGi ? bvih[col] : bhh[col];
        for (int d4 = 0; d4 < DD / 4; d4++) {
            float4 v = *(const float4*)&src[d4 * 4];
            const float* wp = Wt + (size_t)(d4 * 4) * 3 * DD + col;
            g0 += v.x * wp[0] + v.y * wp[3 * DD] + v.z * wp[6 * DD] + v.w * wp[9 * DD];
        }
        if (isGi) gi_lds[col] = g0; else gh_lds[col] = g0;
    }
    __syncthreads();

    float snew = 0.f;
    if (t < DD) {
        float r = 1.f / (1.f + __expf(-(gi_lds[t] + gh_lds[t])));
        float z = 1.f / (1.f + __expf(-(gi_lds[DD + t] + gh_lds[DD + t])));
        float nn_ = tanhf(gi_lds[2 * DD + t] + r * gh_lds[2 * DD + t]);
        snew = (1.f - z) * nn_ + z * prev;
    }
    // --- LN(snew) ---
    {
        float s_ = (t < DD) ? snew : 0.f, sq_ = s_ * s_;
        #pragma unroll
        for (int o = 32; o > 0; o >>= 1) { s_ += __shfl_xor(s_, o); sq_ += __shfl_xor(sq_, o); }
        if (t < DD && (t & 63) == 0) { red[(t >> 6) * 2] = s_; red[(t >> 6) * 2 + 1] = sq_; }
    }
    __syncthreads();
    if (t < DD) {
        float mean = (red[0] + red[2]) * (1.0f / DD);
        float var  = (red[1] + red[3]) * (1.0f / DD) - mean * mean;
        float rstd = rsqrtf(var + LN_EPS);
        tmp[t] = (snew - mean) * rstd * g_ff[t] + b_ff[t];
    }
    __syncthreads();
    // --- W1 matvec, 4-way split over d ---
    {
        int g = t >> 7, c = t & 127;
        if (g < 4) {
            float hp = 0.f;
            for (int d4 = g * 8; d4 < g * 8 + 8; d4++) {
                float4 tv = *(const float4*)&tmp[d4 * 4];
                const float* wp = W1 + (size_t)(d4 * 4) * DD + c;
                hp += tv.x * wp[0] + tv.y * wp[DD] + tv.z * wp[2 * DD] + tv.w * wp[3 * DD];
            }
            pp[g][c] = hp;
        }
    }
    __syncthreads();
    if (t < DD)
        tmp[t] = fmaxf(pp[0][t] + pp[1][t] + pp[2][t] + pp[3][t] + b1[t], 0.f);
    __syncthreads();
    // --- W2 matvec, 4-way split ---
    {
        int g = t >> 7, c = t & 127;
        if (g < 4) {
            float hp = 0.f;
            for (int d4 = g * 8; d4 < g * 8 + 8; d4++) {
                float4 tv = *(const float4*)&tmp[d4 * 4];
                const float* wp = W2 + (size_t)(d4 * 4) * DD + c;
                hp += tv.x * wp[0] + tv.y * wp[DD] + tv.z * wp[2 * DD] + tv.w * wp[3 * DD];
            }
            pp[g][c] = hp;
        }
    }
    __syncthreads();
    float o = 0.f;
    if (t < DD) {
        o = snew + b2[t] + pp[0][t] + pp[1][t] + pp[2][t] + pp[3][t];
        slots[(b * KK + kslot) * DD + t] = o;
    }
    // --- LN(o) ---
    {
        float s_ = (t < DD) ? o : 0.f, sq_ = s_ * s_;
        #pragma unroll
        for (int o2 = 32; o2 > 0; o2 >>= 1) { s_ += __shfl_xor(s_, o2); sq_ += __shfl_xor(sq_, o2); }
        if (t < DD && (t & 63) == 0) { red[(t >> 6) * 2] = s_; red[(t >> 6) * 2 + 1] = sq_; }
    }
    __syncthreads();
    if (t < DD) {
        float mean = (red[0] + red[2]) * (1.0f / DD);
        float var  = (red[1] + red[3]) * (1.0f / DD) - mean * mean;
        float rstd = rsqrtf(var + LN_EPS);
        tmp[t] = (o - mean) * rstd * g_sl[t] + b_sl[t];
    }
    __syncthreads();
    // --- M matvec, 4-way split ---
    {
        int g = t >> 7, c = t & 127;
        if (g < 4) {
            float hp = 0.f;
            for (int d4 = g * 8; d4 < g * 8 + 8; d4++) {
                float4 tv = *(const float4*)&tmp[d4 * 4];
                const float* wp = M + (size_t)(d4 * 4) * DD + c;
                hp += tv.x * wp[0] + tv.y * wp[DD] + tv.z * wp[2 * DD] + tv.w * wp[3 * DD];
            }
            pp[g][c] = hp;
        }
    }
    __syncthreads();
    if (t < DD) {
        float qq = v0[t] + pp[0][t] + pp[1][t] + pp[2][t] + pp[3][t];
        qp[(b * KK + kslot) * DD + t] = SCALE * qq;
        if (last) {
            out_nf[(b * KK + kslot) * DD + t] = o;
            if (t < KK) out_adj[(b * KK + kslot) * KK + t] = 1.0f;
        }
    }
    {
        float cp = (t < DD) ? tmp[t] * wqbk[t] : 0.f;
        #pragma unroll
        for (int o2 = 32; o2 > 0; o2 >>= 1) cp += __shfl_xor(cp, o2);
        if (t < 128 && (t & 63) == 0) red[4 + (t >> 6)] = cp;
    }
    __syncthreads();
    if (t == 0) qc0[b * KK + kslot] = SCALE * (red[4] + red[5] + c1[0]);
}

// ------------------------------------------------------------------
extern "C" void kernel_launch(void* const* d_in, const int* in_sizes, int n_in,
                              void* d_out, int out_size, void* d_ws, size_t ws_size,
                              hipStream_t stream) {
    (void)in_sizes; (void)n_in; (void)out_size; (void)ws_size;
    const float* x        = (const float*)d_in[0];
    const float* noise    = (const float*)d_in[1];
    const float* mu       = (const float*)d_in[2];
    const float* logsigma = (const float*)d_in[3];
    const float* Wq  = (const float*)d_in[4];
    const float* bq  = (const float*)d_in[5];
    const float* Wk  = (const float*)d_in[6];
    const float* bk  = (const float*)d_in[7];
    const float* Wv  = (const float*)d_in[8];
    const float* bv  = (const float*)d_in[9];
    const float* Wih = (const float*)d_in[10];
    const float* Whh = (const float*)d_in[11];
    const float* bih = (const float*)d_in[12];
    const float* bhh = (const float*)d_in[13];
    const float* W1  = (const float*)d_in[14];
    const float* b1  = (const float*)d_in[15];
    const float* W2  = (const float*)d_in[16];
    const float* b2  = (const float*)d_in[17];
    const float* g_in = (const float*)d_in[18];
    const float* b_in = (const float*)d_in[19];
    const float* g_sl = (const float*)d_in[20];
    const float* b_sl = (const float*)d_in[21];
    const float* g_ff = (const float*)d_in[22];
    const float* b_ff = (const float*)d_in[23];

    float* w = (float*)d_ws;
    ushort* xn   = (ushort*)(w + OFF_XN);
    float* qp    = w + OFF_Q;
    float* qc0   = w + OFF_QC0;
    float* slots = w + OFF_SLOTS;
    float* upart = w + OFF_UPART;
    float* dpart = w + OFF_DPART;
    float* sxp   = w + OFF_SXP;
    float* sumx  = w + OFF_SUMX;
    float* WihT  = w + OFF_WIHT;
    float* WhhT  = w + OFF_WHHT;
    float* Wvih  = w + OFF_WVIH;
    float* bvih  = w + OFF_BVIH;
    float* Mw    = w + OFF_M;
    float* v0    = w + OFF_V0;
    float* wqbk  = w + OFF_WQBK;
    float* c1    = w + OFF_C1;

    float* out_nf  = (float*)d_out;                       // [B,K,D]
    float* out_adj = out_nf + BB * KK * DD;               // [B,K,K]
    float* out_s   = out_adj + BB * KK * KK;              // [B,N,K]

    k_prep<<<(PREP_TOTAL + 255) / 256, 256, 0, stream>>>(
        Wih, Whh, Wq, Wk, Wv, bih, bv, bq, bk,
        WihT, WhhT, Wvih, bvih, Mw, v0, wqbk, c1);
    k_ln<<<BB * LNCH, 256, 0, stream>>>(x, g_in, b_in, xn, sxp);
    k_sumx<<<BB, 512, 0, stream>>>(sxp, sumx);
    k_init<<<BB * KK, 128, 0, stream>>>(noise, mu, logsigma, Mw, v0, wqbk, c1,
                                        g_sl, b_sl, slots, qp, qc0);

    for (int it = 0; it < N_ITERS; it++) {
        int last = (it == N_ITERS - 1) ? 1 : 0;
        k_attn<<<BB * NCH, 256, 0, stream>>>(xn, qp, qc0, upart, dpart,
                                             out_s, last);
        k_slot<<<BB * KK, 768, 0, stream>>>(upart, dpart, sumx,
                                            Wvih, bvih, WhhT, bhh, W1, b1, W2, b2,
                                            Mw, v0, wqbk, c1, g_ff, b_ff, g_sl, b_sl,
                                            slots, qp, qc0, out_nf, out_adj, last);
    }
}

// Round 18
// 242.958 us; speedup vs baseline: 64.7756x; 1.0273x over previous
//
#include <hip/hip_runtime.h>
#include <cstdint>

#define BB 8
#define NN 16384
#define DD 128
#define KK 10
#define N_ITERS 7
#define LN_EPS 1e-5f
#define ATT_EPS 1e-8f
#define SCALE 0.08838834764831845f   // D^-0.5

#define LNR 64                 // rows per ln block
#define LNCH (NN / LNR)        // 256 chunks per batch
#define NB 256                 // n per attn block (2 sub-tiles of 128)
#define NCH (NN / NB)          // 64 chunks per batch

typedef __attribute__((ext_vector_type(8))) short bf16x8;
typedef __attribute__((ext_vector_type(4))) float f32x4;

__device__ inline ushort f2bf(float f) {
    uint u = __builtin_bit_cast(uint, f);
    u += 0x7FFFu + ((u >> 16) & 1u);
    return (ushort)(u >> 16);
}
__device__ inline float bf2f(ushort u) {
    return __builtin_bit_cast(float, ((uint)u) << 16);
}

// ---- workspace layout (float units) ----
#define OFF_XN    ((size_t)0)
#define OFF_Q     (OFF_XN + (size_t)BB * NN * DD / 2)
#define OFF_QC0   (OFF_Q + (size_t)BB * KK * DD)
#define OFF_SLOTS (OFF_QC0 + 128)
#define OFF_UPART (OFF_SLOTS + (size_t)BB * KK * DD)
#define OFF_DPART (OFF_UPART + (size_t)BB * NCH * KK * DD)
#define OFF_WIHT  (OFF_DPART + (size_t)BB * NCH * KK)
#define OFF_WHHT  (OFF_WIHT + (size_t)3 * DD * DD)
#define OFF_WVIH  (OFF_WHHT + (size_t)3 * DD * DD)
#define OFF_BVIH  (OFF_WVIH + (size_t)DD * 3 * DD)
#define OFF_M     (OFF_BVIH + (size_t)3 * DD)
#define OFF_V0    (OFF_M + (size_t)DD * DD)
#define OFF_WQBK  (OFF_V0 + (size_t)DD)
#define OFF_C1    (OFF_WQBK + (size_t)DD)

// ------------------------------------------------------------------
// Prep: transposes + folded weight products (one-time, fp32 exact).
__global__ void k_prep(const float* __restrict__ Wih, const float* __restrict__ Whh,
                       const float* __restrict__ Wq, const float* __restrict__ Wk,
                       const float* __restrict__ Wv,
                       const float* __restrict__ bih, const float* __restrict__ bv,
                       const float* __restrict__ bq, const float* __restrict__ bk,
                       float* __restrict__ WihT, float* __restrict__ WhhT,
                       float* __restrict__ Wvih, float* __restrict__ bvih,
                       float* __restrict__ M, float* __restrict__ v0,
                       float* __restrict__ wqbk, float* __restrict__ c1) {
    int idx = blockIdx.x * 256 + threadIdx.x;
    if (idx < 3 * DD * DD) {
        int d = idx / (3 * DD);
        int j = idx % (3 * DD);
        WihT[idx] = Wih[j * DD + d];
        WhhT[idx] = Whh[j * DD + d];
    } else if (idx < 2 * 3 * DD * DD) {
        int i = idx - 3 * DD * DD;
        int d = i / (3 * DD), t = i % (3 * DD);
        float s = 0.f;
        for (int e = 0; e < DD; e++) s += Wv[d * DD + e] * Wih[t * DD + e];
        Wvih[i] = s;
    } else if (idx < 2 * 3 * DD * DD + 3 * DD) {
        int t = idx - 2 * 3 * DD * DD;
        float s = bih[t];
        for (int e = 0; e < DD; e++) s += bv[e] * Wih[t * DD + e];
        bvih[t] = s;
    } else if (idx < 2 * 3 * DD * DD + 3 * DD + DD * DD) {
        int i = idx - (2 * 3 * DD * DD + 3 * DD);
        int d = i / DD, e = i % DD;
        float s = 0.f;
        for (int j = 0; j < DD; j++) s += Wq[d * DD + j] * Wk[e * DD + j];
        M[i] = s;
    } else if (idx < 2 * 3 * DD * DD + 3 * DD + DD * DD + DD) {
        int e = idx - (2 * 3 * DD * DD + 3 * DD + DD * DD);
        float s = 0.f;
        for (int j = 0; j < DD; j++) s += bq[j] * Wk[e * DD + j];
        v0[e] = s;
    } else if (idx < 2 * 3 * DD * DD + 3 * DD + DD * DD + 2 * DD) {
        int d = idx - (2 * 3 * DD * DD + 3 * DD + DD * DD + DD);
        float s = 0.f;
        for (int j = 0; j < DD; j++) s += Wq[d * DD + j] * bk[j];
        wqbk[d] = s;
    } else if (idx == 2 * 3 * DD * DD + 3 * DD + DD * DD + 2 * DD) {
        float s = 0.f;
        for (int j = 0; j < DD; j++) s += bq[j] * bk[j];
        c1[0] = s;
    }
}
#define PREP_TOTAL (2 * 3 * DD * DD + 3 * DD + DD * DD + 2 * DD + 1)

// ------------------------------------------------------------------
// Pure streaming LayerNorm: x -> xn (row-major bf16). No LDS, no barrier.
__global__ __launch_bounds__(256) void k_ln(
        const float* __restrict__ x,
        const float* __restrict__ g_in, const float* __restrict__ b_in,
        ushort* __restrict__ xn) {
    int t = threadIdx.x, blk = blockIdx.x;
    int b = blk >> 8, ch = blk & (LNCH - 1);
    int n0 = ch * LNR;

    int r = t >> 2, p = t & 3;
    const float4* xr = (const float4*)(x + ((size_t)(b * NN + n0 + r)) * DD + p * 32);
    float4 xv[8];
    float s = 0.f, sq = 0.f;
    #pragma unroll
    for (int i = 0; i < 8; i++) {
        xv[i] = xr[i];
        s  += xv[i].x + xv[i].y + xv[i].z + xv[i].w;
        sq += xv[i].x * xv[i].x + xv[i].y * xv[i].y +
              xv[i].z * xv[i].z + xv[i].w * xv[i].w;
    }
    s += __shfl_xor(s, 1);  sq += __shfl_xor(sq, 1);
    s += __shfl_xor(s, 2);  sq += __shfl_xor(sq, 2);
    float mean = s * (1.0f / DD);
    float var  = sq * (1.0f / DD) - mean * mean;
    float rstd = rsqrtf(var + LN_EPS);
    ushort* xno = xn + ((size_t)(b * NN + n0 + r)) * DD + p * 32;
    #pragma unroll
    for (int i = 0; i < 8; i++) {
        int c0 = p * 32 + i * 4;
        ushort4 uv;
        uv.x = f2bf((xv[i].x - mean) * rstd * g_in[c0 + 0] + b_in[c0 + 0]);
        uv.y = f2bf((xv[i].y - mean) * rstd * g_in[c0 + 1] + b_in[c0 + 1]);
        uv.z = f2bf((xv[i].z - mean) * rstd * g_in[c0 + 2] + b_in[c0 + 2]);
        uv.w = f2bf((xv[i].w - mean) * rstd * g_in[c0 + 3] + b_in[c0 + 3]);
        *(ushort4*)(xno + i * 4) = uv;
    }
}

// ------------------------------------------------------------------
__device__ inline void block_stats(float v, float& mean, float& rstd, float* red) {
    float s = v, sq = v * v;
    #pragma unroll
    for (int o = 32; o > 0; o >>= 1) {
        s  += __shfl_down(s, o, 64);
        sq += __shfl_down(sq, o, 64);
    }
    int lane = threadIdx.x & 63, w = threadIdx.x >> 6;
    if (lane == 0) { red[w * 2] = s; red[w * 2 + 1] = sq; }
    __syncthreads();
    float S = red[0] + red[2], SQ = red[1] + red[3];
    mean = S * (1.0f / DD);
    float var = SQ * (1.0f / DD) - mean * mean;
    rstd = rsqrtf(var + LN_EPS);
    __syncthreads();
}

// ------------------------------------------------------------------
__global__ __launch_bounds__(128) void k_init(
        const float* __restrict__ noise, const float* __restrict__ mu,
        const float* __restrict__ logsigma,
        const float* __restrict__ M, const float* __restrict__ v0,
        const float* __restrict__ wqbk, const float* __restrict__ c1,
        const float* __restrict__ g_sl, const float* __restrict__ b_sl,
        float* __restrict__ slots, float* __restrict__ qp,
        float* __restrict__ qc0) {
    int bk_ = blockIdx.x;
    int j = threadIdx.x;
    __shared__ float red[4];
    __shared__ float tmp[DD];
    float s = mu[j] + __expf(logsigma[j]) * noise[bk_ * DD + j];
    slots[bk_ * DD + j] = s;
    float m, rs;
    block_stats(s, m, rs, red);
    tmp[j] = (s - m) * rs * g_sl[j] + b_sl[j];
    __syncthreads();
    float qq = v0[j];
    for (int d = 0; d < DD; d++) qq += tmp[d] * M[d * DD + j];
    qp[bk_ * DD + j] = SCALE * qq;
    float cp = tmp[j] * wqbk[j];
    #pragma unroll
    for (int o = 32; o > 0; o >>= 1) cp += __shfl_xor(cp, o);
    if ((j & 63) == 0) red[j >> 6] = cp;
    __syncthreads();
    if (j == 0) qc0[bk_] = SCALE * (red[0] + red[1] + c1[0]);
}

// ------------------------------------------------------------------
// MFMA attention iteration, NB=256 per block in 2 sub-tiles of 128.
// PV accumulates across sub-tiles in registers; xlds/plds reused.
__global__ __launch_bounds__(256) void k_attn(
        const ushort* __restrict__ xn,
        const float* __restrict__ qp, const float* __restrict__ qc0,
        float* __restrict__ upart, float* __restrict__ dpart,
        float* __restrict__ out_s, int last) {
    __shared__ ushort qpbuf[2176];      // qlds [16][136] then plds [128][17]
    __shared__ ushort xlds[DD * 136];   // [d][n(128)] pad, XOR-swizzled 16B slots
    __shared__ float red2[4][16];
    __shared__ float c0s[16];
#define QLDS(r, c) qpbuf[(r) * 136 + (c)]
#define PLDS(n, k) qpbuf[(n) * 17 + (k)]

    int t = threadIdx.x;
    int blk = blockIdx.x;
    int b  = blk >> 6;
    int ch = blk & (NCH - 1);
    int n0 = ch * NB;
    int w = t >> 6, l = t & 63;
    int lc = l & 15, lg = l >> 4;

    for (int j = t; j < 16 * DD; j += 256) {
        int row = j >> 7, col = j & 127;
        float v = (row < KK) ? qp[((size_t)b * KK + row) * DD + col] : 0.f;
        QLDS(row, col) = f2bf(v);
    }
    if (t < 16) c0s[t] = (t < KK) ? qc0[b * KK + t] : 0.f;
    __syncthreads();

    bf16x8 qb[4];
    #pragma unroll
    for (int ks = 0; ks < 4; ks++)
        qb[ks] = *(const bf16x8*)&QLDS(lc, ks * 32 + lg * 8);
    float c0v = c0s[lc];
    __syncthreads();   // qpbuf now reusable as plds

    f32x4 uacc[2];
    uacc[0] = (f32x4){0.f, 0.f, 0.f, 0.f};
    uacc[1] = (f32x4){0.f, 0.f, 0.f, 0.f};
    float dsum = 0.f;
    bool valid = lc < KK;

    for (int sub = 0; sub < 2; sub++) {
        int nbase = n0 + sub * 128;
        #pragma unroll
        for (int tt = 0; tt < 2; tt++) {
            int nt = w * 2 + tt;    // n-tile 0..7 within sub
            int nrow = nt * 16 + lc;
            const ushort* kb = xn + ((size_t)(b * NN + nbase + nrow)) * DD + lg * 8;
            f32x4 acc = (f32x4){0.f, 0.f, 0.f, 0.f};
            #pragma unroll
            for (int ks = 0; ks < 4; ks++) {
                bf16x8 a = *(const bf16x8*)(kb + ks * 32);   // 16B coalesced
                int dbase = ks * 32 + lg * 8;
                uint swz = (uint)(lg << 4);
                #pragma unroll
                for (int j = 0; j < 8; j++) {
                    uint byteoff = ((uint)(dbase + j) * 272 + (uint)nrow * 2) ^ swz;
                    *(ushort*)((char*)xlds + byteoff) = (ushort)a[j];
                }
                acc = __builtin_amdgcn_mfma_f32_16x16x32_bf16(a, qb[ks], acc, 0, 0, 0);
            }
            #pragma unroll
            for (int r = 0; r < 4; r++) {
                float v = acc[r] + c0v;
                float m = valid ? v : -3.0e38f;
                m = fmaxf(m, __shfl_xor(m, 1));
                m = fmaxf(m, __shfl_xor(m, 2));
                m = fmaxf(m, __shfl_xor(m, 4));
                m = fmaxf(m, __shfl_xor(m, 8));
                float e = valid ? __expf(v - m) : 0.f;
                float s = e;
                s += __shfl_xor(s, 1);
                s += __shfl_xor(s, 2);
                s += __shfl_xor(s, 4);
                s += __shfl_xor(s, 8);
                float p = e / s;
                dsum += p;
                PLDS(nt * 16 + lg * 4 + r, lc) = f2bf(p);
            }
        }
        __syncthreads();    // plds + xlds ready

        bf16x8 pa[4];
        #pragma unroll
        for (int ks = 0; ks < 4; ks++) {
            #pragma unroll
            for (int j = 0; j < 8; j++)
                pa[ks][j] = (short)PLDS(ks * 32 + lg * 8 + j, lc);
        }
        #pragma unroll
        for (int tt = 0; tt < 2; tt++) {
            int dt = w * 2 + tt;
            int drow = dt * 16 + lc;
            uint rswz = (uint)(((drow >> 3) & 3) << 4);
            #pragma unroll
            for (int ks = 0; ks < 4; ks++) {
                uint byteoff = ((uint)drow * 272 + (uint)(ks * 32 + lg * 8) * 2) ^ rswz;
                bf16x8 bf = *(const bf16x8*)((const char*)xlds + byteoff);
                uacc[tt] = __builtin_amdgcn_mfma_f32_16x16x32_bf16(pa[ks], bf, uacc[tt], 0, 0, 0);
            }
        }
        if (last) {
            for (int i = t; i < 128 * KK; i += 256) {
                int n = i / KK, s2 = i - n * KK;
                out_s[((size_t)b * NN + nbase + n) * KK + s2] = bf2f(PLDS(n, s2));
            }
        }
        __syncthreads();    // before next sub overwrites plds/xlds
    }

    dsum += __shfl_xor(dsum, 16);
    dsum += __shfl_xor(dsum, 32);
    if (l < 16) red2[w][l] = dsum;
    __syncthreads();
    if (t < KK)
        dpart[((size_t)b * NCH + ch) * KK + t] =
            red2[0][t] + red2[1][t] + red2[2][t] + red2[3][t];

    float* ud = upart + ((size_t)b * NCH + ch) * KK * DD;
    #pragma unroll
    for (int tt = 0; tt < 2; tt++) {
        int dt = w * 2 + tt;
        #pragma unroll
        for (int r = 0; r < 4; r++) {
            int slot = lg * 4 + r;
            if (slot < KK)
                ud[slot * DD + dt * 16 + lc] = uacc[tt][r];
        }
    }
#undef QLDS
#undef PLDS
}

// ------------------------------------------------------------------
// 768 threads: split-parallel matvecs, short serial chains.
__global__ __launch_bounds__(768) void k_slot(
        const float* __restrict__ upart, const float* __restrict__ dpart,
        const float* __restrict__ Wvih, const float* __restrict__ bvih,
        const float* __restrict__ WhhT, const float* __restrict__ bhh,
        const float* __restrict__ W1, const float* __restrict__ b1,
        const float* __restrict__ W2, const float* __restrict__ b2,
        const float* __restrict__ M, const float* __restrict__ v0,
        const float* __restrict__ wqbk, const float* __restrict__ c1,
        const float* __restrict__ g_ff, const float* __restrict__ b_ff,
        const float* __restrict__ g_sl, const float* __restrict__ b_sl,
        float* __restrict__ slots, float* __restrict__ qp,
        float* __restrict__ qc0,
        float* __restrict__ out_nf, float* __restrict__ out_adj, int last) {
    int blk = blockIdx.x;
    int b = blk / KK, kslot = blk % KK;
    int t = threadIdx.x;
    __shared__ float p_lds[DD], tmp[DD], y_lds[DD];
    __shared__ float gi_lds[3 * DD], gh_lds[3 * DD];
    __shared__ float upr[6][DD];
    __shared__ float pp[4][DD];
    __shared__ float red[8];

    // --- u partial reduce over NCH=64 chunks, 6 groups ---
    {
        int j = t & 127, g = t >> 7;          // g = 0..5
        int c0 = (g * NCH) / 6, cend = ((g + 1) * NCH) / 6;
        const float* up = upart + (size_t)b * NCH * KK * DD + kslot * DD + j;
        float u = 0.f;
        for (int c = c0; c < cend; c++) u += up[(size_t)c * KK * DD];
        upr[g][j] = u;
    }
    // --- denom: 64 chunks, one per thread, shfl reduce ---
    {
        float dsv = 0.f;
        if (t < 64) dsv = dpart[((size_t)b * NCH + t) * KK + kslot];
        #pragma unroll
        for (int o = 32; o > 0; o >>= 1) dsv += __shfl_xor(dsv, o);
        if (t == 0) red[6] = dsv + (float)NN * ATT_EPS;
    }
    __syncthreads();

    float prev = 0.f;
    if (t < DD) {
        float u = upr[0][t] + upr[1][t] + upr[2][t] +
                  upr[3][t] + upr[4][t] + upr[5][t];
        y_lds[t] = u / red[6];   // Yw (eps numerator term ~1e-9, dropped)
        prev = slots[(b * KK + kslot) * DD + t];
        p_lds[t] = prev;
    }
    __syncthreads();

    // --- gi/gh: 768 threads, one gate-column each ---
    {
        bool isGi = t < 384;
        int col = isGi ? t : t - 384;
        const float* Wt  = isGi ? Wvih : WhhT;
        const float* src = isGi ? y_lds : p_lds;
        float g0 = isGi ? bvih[col] : bhh[col];
        for (int d4 = 0; d4 < DD / 4; d4++) {
            float4 v = *(const float4*)&src[d4 * 4];
            const float* wp = Wt + (size_t)(d4 * 4) * 3 * DD + col;
            g0 += v.x * wp[0] + v.y * wp[3 * DD] + v.z * wp[6 * DD] + v.w * wp[9 * DD];
        }
        if (isGi) gi_lds[col] = g0; else gh_lds[col] = g0;
    }
    __syncthreads();

    float snew = 0.f;
    if (t < DD) {
        float r = 1.f / (1.f + __expf(-(gi_lds[t] + gh_lds[t])));
        float z = 1.f / (1.f + __expf(-(gi_lds[DD + t] + gh_lds[DD + t])));
        float nn_ = tanhf(gi_lds[2 * DD + t] + r * gh_lds[2 * DD + t]);
        snew = (1.f - z) * nn_ + z * prev;
    }
    // --- LN(snew) ---
    {
        float s_ = (t < DD) ? snew : 0.f, sq_ = s_ * s_;
        #pragma unroll
        for (int o = 32; o > 0; o >>= 1) { s_ += __shfl_xor(s_, o); sq_ += __shfl_xor(sq_, o); }
        if (t < DD && (t & 63) == 0) { red[(t >> 6) * 2] = s_; red[(t >> 6) * 2 + 1] = sq_; }
    }
    __syncthreads();
    if (t < DD) {
        float mean = (red[0] + red[2]) * (1.0f / DD);
        float var  = (red[1] + red[3]) * (1.0f / DD) - mean * mean;
        float rstd = rsqrtf(var + LN_EPS);
        tmp[t] = (snew - mean) * rstd * g_ff[t] + b_ff[t];
    }
    __syncthreads();
    // --- W1 matvec, 4-way split over d ---
    {
        int g = t >> 7, c = t & 127;
        if (g < 4) {
            float hp = 0.f;
            for (int d4 = g * 8; d4 < g * 8 + 8; d4++) {
                float4 tv = *(const float4*)&tmp[d4 * 4];
                const float* wp = W1 + (size_t)(d4 * 4) * DD + c;
                hp += tv.x * wp[0] + tv.y * wp[DD] + tv.z * wp[2 * DD] + tv.w * wp[3 * DD];
            }
            pp[g][c] = hp;
        }
    }
    __syncthreads();
    if (t < DD)
        tmp[t] = fmaxf(pp[0][t] + pp[1][t] + pp[2][t] + pp[3][t] + b1[t], 0.f);
    __syncthreads();
    // --- W2 matvec, 4-way split ---
    {
        int g = t >> 7, c = t & 127;
        if (g < 4) {
            float hp = 0.f;
            for (int d4 = g * 8; d4 < g * 8 + 8; d4++) {
                float4 tv = *(const float4*)&tmp[d4 * 4];
                const float* wp = W2 + (size_t)(d4 * 4) * DD + c;
                hp += tv.x * wp[0] + tv.y * wp[DD] + tv.z * wp[2 * DD] + tv.w * wp[3 * DD];
            }
            pp[g][c] = hp;
        }
    }
    __syncthreads();
    float o = 0.f;
    if (t < DD) {
        o = snew + b2[t] + pp[0][t] + pp[1][t] + pp[2][t] + pp[3][t];
        slots[(b * KK + kslot) * DD + t] = o;
    }
    // --- LN(o) ---
    {
        float s_ = (t < DD) ? o : 0.f, sq_ = s_ * s_;
        #pragma unroll
        for (int o2 = 32; o2 > 0; o2 >>= 1) { s_ += __shfl_xor(s_, o2); sq_ += __shfl_xor(sq_, o2); }
        if (t < DD && (t & 63) == 0) { red[(t >> 6) * 2] = s_; red[(t >> 6) * 2 + 1] = sq_; }
    }
    __syncthreads();
    if (t < DD) {
        float mean = (red[0] + red[2]) * (1.0f / DD);
        float var  = (red[1] + red[3]) * (1.0f / DD) - mean * mean;
        float rstd = rsqrtf(var + LN_EPS);
        tmp[t] = (o - mean) * rstd * g_sl[t] + b_sl[t];
    }
    __syncthreads();
    // --- M matvec, 4-way split ---
    {
        int g = t >> 7, c = t & 127;
        if (g < 4) {
            float hp = 0.f;
            for (int d4 = g * 8; d4 < g * 8 + 8; d4++) {
                float4 tv = *(const float4*)&tmp[d4 * 4];
                const float* wp = M + (size_t)(d4 * 4) * DD + c;
                hp += tv.x * wp[0] + tv.y * wp[DD] + tv.z * wp[2 * DD] + tv.w * wp[3 * DD];
            }
            pp[g][c] = hp;
        }
    }
    __syncthreads();
    if (t < DD) {
        float qq = v0[t] + pp[0][t] + pp[1][t] + pp[2][t] + pp[3][t];
        qp[(b * KK + kslot) * DD + t] = SCALE * qq;
        if (last) {
            out_nf[(b * KK + kslot) * DD + t] = o;
            if (t < KK) out_adj[(b * KK + kslot) * KK + t] = 1.0f;
        }
    }
    {
        float cp = (t < DD) ? tmp[t] * wqbk[t] : 0.f;
        #pragma unroll
        for (int o2 = 32; o2 > 0; o2 >>= 1) cp += __shfl_xor(cp, o2);
        if (t < 128 && (t & 63) == 0) red[4 + (t >> 6)] = cp;
    }
    __syncthreads();
    if (t == 0) qc0[b * KK + kslot] = SCALE * (red[4] + red[5] + c1[0]);
}

// ------------------------------------------------------------------
extern "C" void kernel_launch(void* const* d_in, const int* in_sizes, int n_in,
                              void* d_out, int out_size, void* d_ws, size_t ws_size,
                              hipStream_t stream) {
    (void)in_sizes; (void)n_in; (void)out_size; (void)ws_size;
    const float* x        = (const float*)d_in[0];
    const float* noise    = (const float*)d_in[1];
    const float* mu       = (const float*)d_in[2];
    const float* logsigma = (const float*)d_in[3];
    const float* Wq  = (const float*)d_in[4];
    const float* bq  = (const float*)d_in[5];
    const float* Wk  = (const float*)d_in[6];
    const float* bk  = (const float*)d_in[7];
    const float* Wv  = (const float*)d_in[8];
    const float* bv  = (const float*)d_in[9];
    const float* Wih = (const float*)d_in[10];
    const float* Whh = (const float*)d_in[11];
    const float* bih = (const float*)d_in[12];
    const float* bhh = (const float*)d_in[13];
    const float* W1  = (const float*)d_in[14];
    const float* b1  = (const float*)d_in[15];
    const float* W2  = (const float*)d_in[16];
    const float* b2  = (const float*)d_in[17];
    const float* g_in = (const float*)d_in[18];
    const float* b_in = (const float*)d_in[19];
    const float* g_sl = (const float*)d_in[20];
    const float* b_sl = (const float*)d_in[21];
    const float* g_ff = (const float*)d_in[22];
    const float* b_ff = (const float*)d_in[23];

    float* w = (float*)d_ws;
    ushort* xn   = (ushort*)(w + OFF_XN);
    float* qp    = w + OFF_Q;
    float* qc0   = w + OFF_QC0;
    float* slots = w + OFF_SLOTS;
    float* upart = w + OFF_UPART;
    float* dpart = w + OFF_DPART;
    float* WihT  = w + OFF_WIHT;
    float* WhhT  = w + OFF_WHHT;
    float* Wvih  = w + OFF_WVIH;
    float* bvih  = w + OFF_BVIH;
    float* Mw    = w + OFF_M;
    float* v0    = w + OFF_V0;
    float* wqbk  = w + OFF_WQBK;
    float* c1    = w + OFF_C1;

    float* out_nf  = (float*)d_out;                       // [B,K,D]
    float* out_adj = out_nf + BB * KK * DD;               // [B,K,K]
    float* out_s   = out_adj + BB * KK * KK;              // [B,N,K]

    k_prep<<<(PREP_TOTAL + 255) / 256, 256, 0, stream>>>(
        Wih, Whh, Wq, Wk, Wv, bih, bv, bq, bk,
        WihT, WhhT, Wvih, bvih, Mw, v0, wqbk, c1);
    k_ln<<<BB * LNCH, 256, 0, stream>>>(x, g_in, b_in, xn);
    k_init<<<BB * KK, 128, 0, stream>>>(noise, mu, logsigma, Mw, v0, wqbk, c1,
                                        g_sl, b_sl, slots, qp, qc0);

    for (int it = 0; it < N_ITERS; it++) {
        int last = (it == N_ITERS - 1) ? 1 : 0;
        k_attn<<<BB * NCH, 256, 0, stream>>>(xn, qp, qc0, upart, dpart,
                                             out_s, last);
        k_slot<<<BB * KK, 768, 0, stream>>>(upart, dpart,
                                            Wvih, bvih, WhhT, bhh, W1, b1, W2, b2,
                                            Mw, v0, wqbk, c1, g_ff, b_ff, g_sl, b_sl,
                                            slots, qp, qc0, out_nf, out_adj, last);
    }
}